// Round 7
// baseline (278.697 us; speedup 1.0000x reference)
//
#include <hip/hip_runtime.h>
#include <hip/hip_bf16.h>
#include <math.h>
#include <stdint.h>

typedef __hip_bfloat16 bf16;
typedef __attribute__((ext_vector_type(8))) short short8;  // 8 bf16 = 4 VGPRs
typedef __attribute__((ext_vector_type(4))) float f32x4;

#define SEQ   2048
#define NPOS  4095          // 2*SEQ-1
#define DIMM  768
#define HEADS 8
#define DK    64
#define HD    512           // HEADS*DK
#define BATCH 2
#define BH    16            // BATCH*HEADS
#define ROWS  4096          // BATCH*SEQ

// ---------------- workspace layout (BYTE offsets), ~44.4 MB ----------------
#define OB_RELK  ((size_t)0)                      // bf16 [8][4095][64], col-swizzled
#define OB_QC    ((size_t)4194304)
#define OB_QP    ((size_t)8388608)
#define OB_K     ((size_t)12582912)
#define OB_V     ((size_t)16777216)               // V^T [bh][64][2048], chunk-swizzled
#define OB_OH    ((size_t)20971520)               // bf16 [4096][512]
// aliased (disjoint lifetimes):
#define OB_EMBH  OB_OH                            // dead after gemm_qr
#define OB_EMBL  ((size_t)(OB_OH + 1572864))
#define OB_XH    ((size_t)25165824)               // dead after gemm_qr
#define OB_XL    ((size_t)31457280)
#define OB_WQKVH ((size_t)37748736)               // dead after gemm_qr
#define OB_WQKVL ((size_t)40108032)
#define OB_OP    ((size_t)25165824)               // f32 [2][16][2048][64] partial O
#define OB_LP    ((size_t)41943040)               // f32 [2][16][2048] partial l
#define OB_WOH   ((size_t)42467328)               // out-proj weights
#define OB_WOL   ((size_t)43253760)
#define OB_WRH   ((size_t)44040192)
#define OB_WRL   ((size_t)44236800)

// RNE float -> bf16 bits (finite inputs only)
__device__ __forceinline__ unsigned f2bf(float f) {
  unsigned u = __float_as_uint(f);
  return (u + 0x7fffu + ((u >> 16) & 1u)) >> 16;
}
__device__ __forceinline__ void split2(float v, unsigned& hb, unsigned& lb) {
  hb = f2bf(v);
  const float back = __uint_as_float(hb << 16);
  lb = f2bf(v - back);
}

// async global->LDS 16B copy (m97 pattern; CK-style addrspace casts).
// l must be wave-uniform; HW writes l + lane*16. g is per-lane.
__device__ __forceinline__ void cp16(const short* g, short* l) {
  __builtin_amdgcn_global_load_lds(
      (__attribute__((address_space(1))) void*)(uintptr_t)(g),
      (__attribute__((address_space(3))) void*)(uint32_t)(uintptr_t)(l),
      16, 0, 0);
}

// ---------------- 1. fused prep: pos_emb + conv_split + 5 transposes ----------------
__global__ __launch_bounds__(256) void prep_all(
    const float* __restrict__ x,
    const float* __restrict__ Wq, const float* __restrict__ Wk,
    const float* __restrict__ Wv, const float* __restrict__ Wout,
    const float* __restrict__ Wrel,
    short* __restrict__ eh, short* __restrict__ el,
    short* __restrict__ xh, short* __restrict__ xl,
    short* __restrict__ wqkvh, short* __restrict__ wqkvl,
    short* __restrict__ woh, short* __restrict__ wol,
    short* __restrict__ wrh, short* __restrict__ wrl) {
  __shared__ float tile[32][33];
  const int blk = blockIdx.x;
  const int t = threadIdx.x;

  if (blk < 512) {
    const int row = blk * 8 + (t >> 5);
    const int j   = t & 31;
    if (row >= NPOS) {
      for (int c = j; c < 192; c += 32) { eh[(size_t)row * 192 + c] = 0; el[(size_t)row * 192 + c] = 0; }
      return;
    }
    const float dist = (float)(row - (SEQ - 1));
    const float ad   = fabsf(dist);
    const float hl    = exp2f(3.0f + 8.0f * (float)j / 31.0f);
    const float f_exp = exp2f(-ad / hl);
    const float width = exp2f((float)(j + 1)) - 1.0f;
    const float f_cm  = (width > ad) ? 1.0f : 0.0f;
    float prob;
    if (ad > 0.0f) {
      const float c   = 4.0f * (float)((j + 1) * (j + 1));
      const float r   = (float)(j + 1) / 16.0f;
      const float lu  = (c - 1.0f) * logf(ad) - r * ad;
      const float ln_ = lgammaf(c) - c * logf(r);
      prob = expf(lu - ln_) + 1e-8f;
    } else {
      prob = 1e-8f;
    }
    float mx = prob;
    for (int off = 16; off; off >>= 1) mx = fmaxf(mx, __shfl_xor(mx, off, 32));
    const float f_g = prob / mx;
    const float s = (dist > 0.f) ? 1.f : ((dist < 0.f) ? -1.f : 0.f);
    const float vals[6] = {f_exp, f_cm, f_g, s * f_exp, s * f_cm, s * f_g};
    short* ph = eh + (size_t)row * 192;
    short* pl = el + (size_t)row * 192;
#pragma unroll
    for (int q = 0; q < 6; q++) {
      unsigned hb, lb;
      split2(vals[q], hb, lb);
      ph[q * 32 + j] = (short)hb;
      pl[q * 32 + j] = (short)lb;
    }
    return;
  }

  if (blk < 3584) {
    const int i = (blk - 512) * 256 + t;
    const float4 v = ((const float4*)x)[i];
    unsigned h0, l0, h1, l1, h2, l2, h3, l3;
    split2(v.x, h0, l0); split2(v.y, h1, l1); split2(v.z, h2, l2); split2(v.w, h3, l3);
    *(uint2*)&xh[(size_t)i * 4] = make_uint2(h0 | (h1 << 16), h2 | (h3 << 16));
    *(uint2*)&xl[(size_t)i * 4] = make_uint2(l0 | (l1 << 16), l2 | (l3 << 16));
    return;
  }

  const float* src; short* dh; short* dl; int R, C, local;
  if (blk < 3968)      { local = blk - 3584; src = Wq;   dh = wqkvh;               dl = wqkvl;               R = DIMM; C = HD; }
  else if (blk < 4352) { local = blk - 3968; src = Wk;   dh = wqkvh + 512 * DIMM;  dl = wqkvl + 512 * DIMM;  R = DIMM; C = HD; }
  else if (blk < 4736) { local = blk - 4352; src = Wv;   dh = wqkvh + 1024 * DIMM; dl = wqkvl + 1024 * DIMM; R = DIMM; C = HD; }
  else if (blk < 5120) { local = blk - 4736; src = Wout; dh = woh;  dl = wol;  R = HD;  C = DIMM; }
  else                 { local = blk - 5120; src = Wrel; dh = wrh;  dl = wrl;  R = 192; C = HD; }
  const int ctiles = C / 32;
  const int c0 = (local % ctiles) * 32, r0 = (local / ctiles) * 32;
  {
    const int lr = t >> 3, lc = (t & 7) * 4;
    const float4 v = *(const float4*)&src[(size_t)(r0 + lr) * C + c0 + lc];
    tile[lr][lc] = v.x; tile[lr][lc + 1] = v.y; tile[lr][lc + 2] = v.z; tile[lr][lc + 3] = v.w;
  }
  __syncthreads();
  const int nn = t >> 3, kb = (t & 7) * 4;
  unsigned hb[4], lb[4];
#pragma unroll
  for (int e = 0; e < 4; e++) split2(tile[kb + e][nn], hb[e], lb[e]);
  const size_t o = (size_t)(c0 + nn) * R + r0 + kb;
  *(uint2*)&dh[o] = make_uint2(hb[0] | (hb[1] << 16), hb[2] | (hb[3] << 16));
  *(uint2*)&dl[o] = make_uint2(lb[0] | (lb[1] << 16), lb[2] | (lb[3] << 16));
}

// ---------------- 2. unified qkv+relk GEMM, async global_load_lds staging ----------------
// grid 512: [0,384)=qkv (K=768), [384,512)=relk (K=192). 128x128 tile, BK=32.
// V epilogue writes V^T [bh][d][s] with per-64-chunk col swizzle s ^= ((d&7)<<3);
// relk epilogue writes d ^= ((m&7)<<3). Both consumed by attn (rule #21:
// pre-swizzled-global; V via cp16+swizzled LDS read, rel via swizzled global read).
__global__ __launch_bounds__(256) void gemm_qr(
    const short* __restrict__ xh, const short* __restrict__ xl,
    const short* __restrict__ wqkvh, const short* __restrict__ wqkvl,
    const short* __restrict__ eh, const short* __restrict__ el,
    const short* __restrict__ wrh, const short* __restrict__ wrl,
    const float* __restrict__ cb, const float* __restrict__ pb,
    bf16* __restrict__ oq, bf16* __restrict__ oqp,
    bf16* __restrict__ ok, short* __restrict__ vtw,
    bf16* __restrict__ relk) {
  __shared__ short AsH[128][32];
  __shared__ short AsL[128][32];
  __shared__ short BsH[128][32];
  __shared__ short BsL[128][32];

  const int bx = blockIdx.x;
  const bool isq = bx < 384;
  const int lbx = isq ? bx : bx - 384;
  const int mt = lbx & 31, ntile = lbx >> 5;
  const int m0 = mt * 128, n0 = ntile * 128;
  const int KD = isq ? DIMM : 192;
  const short* Ah = isq ? xh : eh;
  const short* Al = isq ? xl : el;
  const short* Bh = isq ? wqkvh : wrh;
  const short* Bl = isq ? wqkvl : wrl;

  const int t = threadIdx.x, lane = t & 63, w = t >> 6;
  const int quad = lane >> 4, l15 = lane & 15;
  const int wm = (w >> 1) * 64, wn = (w & 1) * 64;

  const int srow = w * 32 + (lane >> 2);   // + c*16
  const int skof = (lane & 3) * 8;         // shorts within 64B row

  f32x4 acc[4][4];
#pragma unroll
  for (int i = 0; i < 4; i++)
#pragma unroll
    for (int j = 0; j < 4; j++) acc[i][j] = (f32x4){0.f, 0.f, 0.f, 0.f};

  for (int k0 = 0; k0 < KD; k0 += 32) {
    __syncthreads();
#pragma unroll
    for (int c = 0; c < 2; c++) {
      const size_t ra = (size_t)(m0 + srow + c * 16) * KD + k0 + skof;
      const size_t rb = (size_t)(n0 + srow + c * 16) * KD + k0 + skof;
      cp16(&Ah[ra], &AsH[w * 32 + c * 16][0]);
      cp16(&Al[ra], &AsL[w * 32 + c * 16][0]);
      cp16(&Bh[rb], &BsH[w * 32 + c * 16][0]);
      cp16(&Bl[rb], &BsL[w * 32 + c * 16][0]);
    }
    __syncthreads();   // drains vmcnt(0): async data landed

    short8 amh[4], aml[4], bnh[4], bnl[4];
#pragma unroll
    for (int i = 0; i < 4; i++) {
      amh[i] = *(const short8*)&AsH[wm + i * 16 + l15][quad * 8];
      aml[i] = *(const short8*)&AsL[wm + i * 16 + l15][quad * 8];
      bnh[i] = *(const short8*)&BsH[wn + i * 16 + l15][quad * 8];
      bnl[i] = *(const short8*)&BsL[wn + i * 16 + l15][quad * 8];
    }
#pragma unroll
    for (int i = 0; i < 4; i++) {
#pragma unroll
      for (int j = 0; j < 4; j++) {
        acc[i][j] = __builtin_amdgcn_mfma_f32_16x16x32_bf16(amh[i], bnh[j], acc[i][j], 0, 0, 0);
        acc[i][j] = __builtin_amdgcn_mfma_f32_16x16x32_bf16(amh[i], bnl[j], acc[i][j], 0, 0, 0);
        acc[i][j] = __builtin_amdgcn_mfma_f32_16x16x32_bf16(aml[i], bnh[j], acc[i][j], 0, 0, 0);
      }
    }
  }

  if (isq) {
    const int sel = ntile >> 2;   // 0=q,1=k,2=v
    if (sel == 2) {
      // V^T write, swizzled: s' = s ^ ((d&7)<<3) within the 64-aligned chunk.
      // s base is 4-aligned; XOR touches bits 3..5 -> uint2 stays contiguous.
#pragma unroll
      for (int i = 0; i < 4; i++) {
#pragma unroll
        for (int j = 0; j < 4; j++) {
          const int n = n0 + wn + j * 16 + l15;
          const int hd_ = n & 511, hh = hd_ >> 6, d = hd_ & 63;
          const int m = m0 + wm + i * 16 + quad * 4;
          const int b = m >> 11, s = m & 2047;
          const int s_swz = s ^ ((d & 7) << 3);
          const uint2 pk = make_uint2(
              f2bf(acc[i][j][0]) | (f2bf(acc[i][j][1]) << 16),
              f2bf(acc[i][j][2]) | (f2bf(acc[i][j][3]) << 16));
          *(uint2*)&vtw[(((size_t)(b * HEADS + hh) * DK + d) * SEQ) + s_swz] = pk;
        }
      }
    } else {
#pragma unroll
      for (int i = 0; i < 4; i++) {
#pragma unroll
        for (int j = 0; j < 4; j++) {
          const int n = n0 + wn + j * 16 + l15;
          const int hd_ = n & 511, hh = hd_ >> 6, d = hd_ & 63;
#pragma unroll
          for (int g = 0; g < 4; g++) {
            const int m = m0 + wm + i * 16 + quad * 4 + g;
            const int b = m >> 11, s = m & 2047;
            const size_t idx = (((size_t)(b * HEADS + hh) * SEQ) + s) * DK + d;
            const float v = acc[i][j][g];
            if (sel == 0) {
              const float sv = v * 0.125f;   // dk^-0.5
              oq[idx]  = __float2bfloat16(sv + cb[hh * DK + d]);
              oqp[idx] = __float2bfloat16(sv + pb[hh * DK + d]);
            } else {
              ok[idx] = __float2bfloat16(v);
            }
          }
        }
      }
    }
  } else {
    // relk write, swizzled: d' = d ^ ((m&7)<<3)
#pragma unroll
    for (int i = 0; i < 4; i++) {
#pragma unroll
      for (int j = 0; j < 4; j++) {
        const int n = n0 + wn + j * 16 + l15;
        const int hh = n >> 6, d = n & 63;
#pragma unroll
        for (int g = 0; g < 4; g++) {
          const int m = m0 + wm + i * 16 + quad * 4 + g;
          if (m < NPOS)
            relk[((size_t)hh * NPOS + m) * DK + (d ^ ((m & 7) << 3))] =
                __float2bfloat16(acc[i][j][g]);
        }
      }
    }
  }
}

// ---------------- 3. out-projection GEMM, async staging ----------------
__global__ __launch_bounds__(256) void out_gemm(
    const short* __restrict__ Ahp,
    const short* __restrict__ Bhp, const short* __restrict__ Blp,
    const float* __restrict__ bias, float* __restrict__ ofp) {
  __shared__ short AsH[128][32];
  __shared__ short BsH[128][32];
  __shared__ short BsL[128][32];

  const int t = threadIdx.x, lane = t & 63, w = t >> 6;
  const int quad = lane >> 4, l15 = lane & 15;
  const int wm = (w >> 1) * 64, wn = (w & 1) * 64;
  const int m0 = blockIdx.x * 128, n0 = blockIdx.y * 128;
  const int srow = w * 32 + (lane >> 2);
  const int skof = (lane & 3) * 8;

  f32x4 acc[4][4];
#pragma unroll
  for (int i = 0; i < 4; i++)
#pragma unroll
    for (int j = 0; j < 4; j++) acc[i][j] = (f32x4){0.f, 0.f, 0.f, 0.f};

  for (int k0 = 0; k0 < HD; k0 += 32) {
    __syncthreads();
#pragma unroll
    for (int c = 0; c < 2; c++) {
      const size_t ra = (size_t)(m0 + srow + c * 16) * HD + k0 + skof;
      const size_t rb = (size_t)(n0 + srow + c * 16) * HD + k0 + skof;
      cp16(&Ahp[ra], &AsH[w * 32 + c * 16][0]);
      cp16(&Bhp[rb], &BsH[w * 32 + c * 16][0]);
      cp16(&Blp[rb], &BsL[w * 32 + c * 16][0]);
    }
    __syncthreads();

    short8 amh[4], bnh[4], bnl[4];
#pragma unroll
    for (int i = 0; i < 4; i++) {
      amh[i] = *(const short8*)&AsH[wm + i * 16 + l15][quad * 8];
      bnh[i] = *(const short8*)&BsH[wn + i * 16 + l15][quad * 8];
      bnl[i] = *(const short8*)&BsL[wn + i * 16 + l15][quad * 8];
    }
#pragma unroll
    for (int i = 0; i < 4; i++) {
#pragma unroll
      for (int j = 0; j < 4; j++) {
        acc[i][j] = __builtin_amdgcn_mfma_f32_16x16x32_bf16(amh[i], bnh[j], acc[i][j], 0, 0, 0);
        acc[i][j] = __builtin_amdgcn_mfma_f32_16x16x32_bf16(amh[i], bnl[j], acc[i][j], 0, 0, 0);
      }
    }
  }

#pragma unroll
  for (int i = 0; i < 4; i++) {
#pragma unroll
    for (int j = 0; j < 4; j++) {
      const int n = n0 + wn + j * 16 + l15;
      const float bv = bias[n];
#pragma unroll
      for (int g = 0; g < 4; g++) {
        const int m = m0 + wm + i * 16 + quad * 4 + g;
        ofp[(size_t)m * DIMM + n] = acc[i][j][g] + bv;
      }
    }
  }
}

// ---------------- 4. attention: DS-traffic-minimized, LDS = 24576 ----------------
// R6 analysis: LDS pipe ~90% busy (18 b128 reads + 16 u16 writes + 16 bperm +
// staging per wave-tile) -> matrix pipe starves. Cuts:
//  - rel windows DIRECT from global: same access shape as K (16 x 128B rows,
//    16B/lane), which has been direct all along. Deletes rel ring + its cp16s
//    + 8 DS b128 reads/tile. (R1's regression was V^T's 4KB-stride scatter,
//    not this pattern.)
//  - V^T via conflict-free cp16 again, double-buffered (kills R6's 1.05M
//    ds_write conflicts and the extra barrier). 1 barrier/tile.
//  - LDS = 2x8192 (VtB) + 8192 (Pw) = 24576 -> ~6 blk/CU (occupancy ~70%).
__global__ __launch_bounds__(256) void attn_mfma4(
    const short* __restrict__ qc, const short* __restrict__ qp,
    const short* __restrict__ kg, const short* __restrict__ vt,
    const short* __restrict__ relk,
    float* __restrict__ Op, float* __restrict__ Lp) {
  __shared__ __align__(16) short VtB[2][64 * 64];    // V^T tile, double-buffered
  __shared__ __align__(16) short Pw[4][16][64];      // per-wave P, XOR-swizzled

  const int bid = blockIdx.x;
  const int swz = (bid & 7) * 128 + (bid >> 3);   // bijective: 1024 % 8 == 0
  const int i0  = (swz & 31) * 64;
  const int bh  = (swz >> 5) & 15;
  const int z   = swz >> 9;
  const int h   = bh & 7;
  const int jb  = z * (SEQ / 2);

  const int t    = threadIdx.x;
  const int lane = t & 63;
  const int w    = t >> 6;
  const int quad = lane >> 4;
  const int l15  = lane & 15;
  const int x    = (l15 & 7) << 3;      // swizzle key (shorts); == (m&7)<<3 for rel rows

  short8 qcA[2], qpA[2];
  {
    const size_t qrow = ((size_t)bh * SEQ + i0 + w * 16 + l15) * DK + quad * 8;
    qcA[0] = *(const short8*)(qc + qrow);
    qcA[1] = *(const short8*)(qc + qrow + 32);
    qpA[0] = *(const short8*)(qp + qrow);
    qpA[1] = *(const short8*)(qp + qrow + 32);
  }

  int idxg[4]; bool selg[4];
#pragma unroll
  for (int g = 0; g < 4; g++) {
    const int r = quad * 4 + g;
    idxg[g] = (((lane & 48) | ((l15 + 15 - r) & 15)) << 2);
    selg[g] = (l15 <= r);
  }

  short8 ones8;
#pragma unroll
  for (int e = 0; e < 8; e++) ones8[e] = (short)0x3F80;   // bf16 1.0

  f32x4 oacc[4];
#pragma unroll
  for (int dt = 0; dt < 4; dt++) oacc[dt] = (f32x4){0.f, 0.f, 0.f, 0.f};
  f32x4 lacc = (f32x4){0.f, 0.f, 0.f, 0.f};

  const short* kbase = kg + (size_t)bh * SEQ * DK;
  const short* vbase = vt + (size_t)bh * DK * SEQ;
  // rel rows indexed as (j - i0 + 1984) + offset; fold head base + (1984 - i0).
  const short* rbase = relk + ((size_t)(h * NPOS + 1984 - i0)) * DK;

  const int rb_w = 48 - 16 * w;

  // stage V^T tile at j0n into buffer nxt: 8 cp16 per block, 2 per wave
  auto STAGEV = [&](int nxt, int j0n) {
#pragma unroll
    for (int cc = 0; cc < 2; cc++) {
      const int c = w * 2 + cc;
      cp16(vbase + (size_t)(c * 8 + (lane >> 3)) * SEQ + j0n + (lane & 7) * 8,
           &VtB[nxt][c * 512]);
    }
  };

  // ---- prologue ----
  STAGEV(0, jb);
  // carry init: bpermuted rel window 0 of tile 0 (direct global, swizzled cols)
  f32x4 bpp_carry;
  {
    const short* rl = rbase + (size_t)(jb + rb_w + l15) * DK;
    short8 b0 = *(const short8*)(rl + ((quad * 8) ^ x));
    short8 b1 = *(const short8*)(rl + ((quad * 8 + 32) ^ x));
    f32x4 a = (f32x4){0.f, 0.f, 0.f, 0.f};
    a = __builtin_amdgcn_mfma_f32_16x16x32_bf16(qpA[0], b0, a, 0, 0, 0);
    a = __builtin_amdgcn_mfma_f32_16x16x32_bf16(qpA[1], b1, a, 0, 0, 0);
#pragma unroll
    for (int g = 0; g < 4; g++)
      bpp_carry[g] = __int_as_float(__builtin_amdgcn_ds_bpermute(idxg[g], __float_as_int(a[g])));
  }
  __syncthreads();   // V tile 0 landed (vmcnt drain hidden under carry init)

  int cur = 0;
  for (int jt = 0; jt < 16; jt++) {
    const int j0 = jb + jt * 64;

    // issue next V tile's staging first: rides under this tile's compute
    if (jt < 15) STAGEV(cur ^ 1, j0 + 64);

    // QK^T: K fragments direct from global (unswizzled)
    f32x4 sacc[4];
#pragma unroll
    for (int nt = 0; nt < 4; nt++) {
      const short* kr = kbase + (size_t)(j0 + nt * 16 + l15) * DK + quad * 8;
      short8 b0 = *(const short8*)kr;
      short8 b1 = *(const short8*)(kr + 32);
      f32x4 a = (f32x4){0.f, 0.f, 0.f, 0.f};
      a = __builtin_amdgcn_mfma_f32_16x16x32_bf16(qcA[0], b0, a, 0, 0, 0);
      a = __builtin_amdgcn_mfma_f32_16x16x32_bf16(qcA[1], b1, a, 0, 0, 0);
      sacc[nt] = a;
    }

    f32x4 bpp = bpp_carry;

#pragma unroll
    for (int nt = 0; nt < 4; nt++) {
      f32x4 rcur;
      {
        // rel window nt+1 direct from global (swizzled cols, key = (l15&7))
        const short* rl = rbase + (size_t)(j0 + 16 + rb_w + nt * 16 + l15) * DK;
        short8 b0 = *(const short8*)(rl + ((quad * 8) ^ x));
        short8 b1 = *(const short8*)(rl + ((quad * 8 + 32) ^ x));
        f32x4 a = (f32x4){0.f, 0.f, 0.f, 0.f};
        a = __builtin_amdgcn_mfma_f32_16x16x32_bf16(qpA[0], b0, a, 0, 0, 0);
        a = __builtin_amdgcn_mfma_f32_16x16x32_bf16(qpA[1], b1, a, 0, 0, 0);
        rcur = a;
      }
      f32x4 bpc;
#pragma unroll
      for (int g = 0; g < 4; g++)
        bpc[g] = __int_as_float(__builtin_amdgcn_ds_bpermute(idxg[g], __float_as_int(rcur[g])));
#pragma unroll
      for (int g = 0; g < 4; g++) {
        const float relv = selg[g] ? bpp[g] : bpc[g];
        const float s = sacc[nt][g] + relv;
        const float p = __expf(s - 12.0f);
        const int prow = quad * 4 + g;
        Pw[w][prow][(nt * 16 + l15) ^ ((prow & 7) << 3)] = (short)f2bf(p);
      }
      bpp = bpc;
    }
    bpp_carry = bpp;   // window 4 of this tile == window 0 of the next

#pragma unroll
    for (int ks = 0; ks < 2; ks++) {
      short8 pA = *(const short8*)&Pw[w][l15][(ks * 32 + quad * 8) ^ x];
      lacc = __builtin_amdgcn_mfma_f32_16x16x32_bf16(pA, ones8, lacc, 0, 0, 0);
#pragma unroll
      for (int dt = 0; dt < 4; dt++) {
        const short* vl = &VtB[cur][(dt * 16 + l15) * 64 + ((ks * 32 + quad * 8) ^ x)];
        short8 vB = *(const short8*)vl;
        oacc[dt] = __builtin_amdgcn_mfma_f32_16x16x32_bf16(pA, vB, oacc[dt], 0, 0, 0);
      }
    }

    __syncthreads();   // publishes prefetch (landed under compute); protects swap
    cur ^= 1;
  }

  const size_t obase = ((size_t)(z * BH + bh) * SEQ + i0 + w * 16);
#pragma unroll
  for (int g = 0; g < 4; g++) {
    const int r = quad * 4 + g;
#pragma unroll
    for (int dt = 0; dt < 4; dt++)
      Op[(obase + r) * DK + dt * 16 + l15] = oacc[dt][g];
    if (l15 == 0) Lp[obase + r] = lacc[g];
  }
}

// ---------------- 5. merge halves -> oh bf16 ----------------
__global__ void merge_kernel(const float* __restrict__ Op, const float* __restrict__ Lp,
                             bf16* __restrict__ oh) {
  const int gid = blockIdx.x * 256 + threadIdx.x;
  const int m = gid >> 7;
  const int n0 = (gid & 127) * 4;
  const int b = m >> 11, s = m & 2047;
  const int hh = n0 >> 6, d0 = n0 & 63;
  const int bh = b * HEADS + hh;
  const float l = Lp[(size_t)bh * SEQ + s] + Lp[((size_t)BH + bh) * SEQ + s];
  const float inv = 1.0f / l;
  const float4 o0 = *(const float4*)&Op[((size_t)bh * SEQ + s) * DK + d0];
  const float4 o1 = *(const float4*)&Op[(((size_t)BH + bh) * SEQ + s) * DK + d0];
  *(uint2*)&oh[(size_t)m * HD + n0] = make_uint2(
      f2bf((o0.x + o1.x) * inv) | (f2bf((o0.y + o1.y) * inv) << 16),
      f2bf((o0.z + o1.z) * inv) | (f2bf((o0.w + o1.w) * inv) << 16));
}

// ---------------- launch ----------------
extern "C" void kernel_launch(void* const* d_in, const int* in_sizes, int n_in,
                              void* d_out, int out_size, void* d_ws, size_t ws_size,
                              hipStream_t stream) {
  (void)in_sizes; (void)n_in; (void)out_size; (void)ws_size;
  const float* x    = (const float*)d_in[0];
  const float* Wq   = (const float*)d_in[1];
  const float* Wk   = (const float*)d_in[2];
  const float* Wv   = (const float*)d_in[3];
  const float* Wrel = (const float*)d_in[4];
  const float* Wout = (const float*)d_in[5];
  const float* bout = (const float*)d_in[6];
  const float* cb   = (const float*)d_in[7];
  const float* pb   = (const float*)d_in[8];
  float* out = (float*)d_out;

  char* ws = (char*)d_ws;
  bf16*  relk = (bf16*)(ws + OB_RELK);
  bf16*  qc   = (bf16*)(ws + OB_QC);
  bf16*  qp   = (bf16*)(ws + OB_QP);
  bf16*  kk   = (bf16*)(ws + OB_K);
  short* vt   = (short*)(ws + OB_V);    // V^T written directly by gemm_qr (swizzled)
  bf16*  oh   = (bf16*)(ws + OB_OH);
  float* Opb  = (float*)(ws + OB_OP);
  float* Lpb  = (float*)(ws + OB_LP);
  short* embh = (short*)(ws + OB_EMBH);
  short* embl = (short*)(ws + OB_EMBL);
  short* xh   = (short*)(ws + OB_XH);
  short* xl   = (short*)(ws + OB_XL);
  short* wqh  = (short*)(ws + OB_WQKVH);
  short* wql  = (short*)(ws + OB_WQKVL);
  short* woh  = (short*)(ws + OB_WOH);
  short* wol  = (short*)(ws + OB_WOL);
  short* wrh  = (short*)(ws + OB_WRH);
  short* wrl  = (short*)(ws + OB_WRL);

  hipLaunchKernelGGL(prep_all, dim3(5216), dim3(256), 0, stream,
                     x, Wq, Wk, Wv, Wout, Wrel,
                     embh, embl, xh, xl, wqh, wql, woh, wol, wrh, wrl);
  hipLaunchKernelGGL(gemm_qr, dim3(512), dim3(256), 0, stream,
                     xh, xl, wqh, wql, embh, embl, wrh, wrl,
                     cb, pb, qc, qp, kk, vt, relk);
  hipLaunchKernelGGL(attn_mfma4, dim3(1024), dim3(256), 0, stream,
                     (const short*)qc, (const short*)qp, (const short*)kk,
                     (const short*)vt, (const short*)relk, Opb, Lpb);
  hipLaunchKernelGGL(merge_kernel, dim3(ROWS * (HD / 4) / 256), dim3(256), 0, stream,
                     Opb, Lpb, oh);
  hipLaunchKernelGGL(out_gemm, dim3(32, 6), dim3(256), 0, stream,
                     (const short*)oh, woh, wol, bout, out);
}

// Round 9
// 223.375 us; speedup vs baseline: 1.2477x; 1.2477x over previous
//
#include <hip/hip_runtime.h>
#include <hip/hip_bf16.h>
#include <math.h>
#include <stdint.h>

typedef __hip_bfloat16 bf16;
typedef __attribute__((ext_vector_type(8))) short short8;  // 8 bf16 = 4 VGPRs
typedef __attribute__((ext_vector_type(4))) float f32x4;

#define SEQ   2048
#define NPOS  4095          // 2*SEQ-1
#define DIMM  768
#define HEADS 8
#define DK    64
#define HD    512           // HEADS*DK
#define BATCH 2
#define BH    16            // BATCH*HEADS
#define ROWS  4096          // BATCH*SEQ

// ---------------- workspace layout (BYTE offsets), ~44.4 MB ----------------
#define OB_RELK  ((size_t)0)                      // bf16 [8][4095][64], col-swizzled
#define OB_QC    ((size_t)4194304)
#define OB_QP    ((size_t)8388608)
#define OB_K     ((size_t)12582912)
#define OB_V     ((size_t)16777216)               // V^T [bh][64][2048], chunk-swizzled
#define OB_OH    ((size_t)20971520)               // bf16 [4096][512]
// aliased (disjoint lifetimes):
#define OB_EMBH  OB_OH                            // dead after gemm_qr
#define OB_EMBL  ((size_t)(OB_OH + 1572864))
#define OB_XH    ((size_t)25165824)               // dead after gemm_qr
#define OB_XL    ((size_t)31457280)
#define OB_WQKVH ((size_t)37748736)               // dead after gemm_qr
#define OB_WQKVL ((size_t)40108032)
#define OB_OP    ((size_t)25165824)               // f32 [2][16][2048][64] partial O
#define OB_LP    ((size_t)41943040)               // f32 [2][16][2048] partial l
#define OB_WOH   ((size_t)42467328)               // out-proj weights
#define OB_WOL   ((size_t)43253760)
#define OB_WRH   ((size_t)44040192)
#define OB_WRL   ((size_t)44236800)

// RNE float -> bf16 bits (finite inputs only)
__device__ __forceinline__ unsigned f2bf(float f) {
  unsigned u = __float_as_uint(f);
  return (u + 0x7fffu + ((u >> 16) & 1u)) >> 16;
}
__device__ __forceinline__ void split2(float v, unsigned& hb, unsigned& lb) {
  hb = f2bf(v);
  const float back = __uint_as_float(hb << 16);
  lb = f2bf(v - back);
}

// async global->LDS 16B copy (m97 pattern; CK-style addrspace casts).
// l must be wave-uniform; HW writes l + lane*16. g is per-lane.
__device__ __forceinline__ void cp16(const short* g, short* l) {
  __builtin_amdgcn_global_load_lds(
      (__attribute__((address_space(1))) void*)(uintptr_t)(g),
      (__attribute__((address_space(3))) void*)(uint32_t)(uintptr_t)(l),
      16, 0, 0);
}

// ---------------- 1. fused prep: pos_emb + conv_split + 5 transposes ----------------
__global__ __launch_bounds__(256) void prep_all(
    const float* __restrict__ x,
    const float* __restrict__ Wq, const float* __restrict__ Wk,
    const float* __restrict__ Wv, const float* __restrict__ Wout,
    const float* __restrict__ Wrel,
    short* __restrict__ eh, short* __restrict__ el,
    short* __restrict__ xh, short* __restrict__ xl,
    short* __restrict__ wqkvh, short* __restrict__ wqkvl,
    short* __restrict__ woh, short* __restrict__ wol,
    short* __restrict__ wrh, short* __restrict__ wrl) {
  __shared__ float tile[32][33];
  const int blk = blockIdx.x;
  const int t = threadIdx.x;

  if (blk < 512) {
    const int row = blk * 8 + (t >> 5);
    const int j   = t & 31;
    if (row >= NPOS) {
      for (int c = j; c < 192; c += 32) { eh[(size_t)row * 192 + c] = 0; el[(size_t)row * 192 + c] = 0; }
      return;
    }
    const float dist = (float)(row - (SEQ - 1));
    const float ad   = fabsf(dist);
    const float hl    = exp2f(3.0f + 8.0f * (float)j / 31.0f);
    const float f_exp = exp2f(-ad / hl);
    const float width = exp2f((float)(j + 1)) - 1.0f;
    const float f_cm  = (width > ad) ? 1.0f : 0.0f;
    float prob;
    if (ad > 0.0f) {
      const float c   = 4.0f * (float)((j + 1) * (j + 1));
      const float r   = (float)(j + 1) / 16.0f;
      const float lu  = (c - 1.0f) * logf(ad) - r * ad;
      const float ln_ = lgammaf(c) - c * logf(r);
      prob = expf(lu - ln_) + 1e-8f;
    } else {
      prob = 1e-8f;
    }
    float mx = prob;
    for (int off = 16; off; off >>= 1) mx = fmaxf(mx, __shfl_xor(mx, off, 32));
    const float f_g = prob / mx;
    const float s = (dist > 0.f) ? 1.f : ((dist < 0.f) ? -1.f : 0.f);
    const float vals[6] = {f_exp, f_cm, f_g, s * f_exp, s * f_cm, s * f_g};
    short* ph = eh + (size_t)row * 192;
    short* pl = el + (size_t)row * 192;
#pragma unroll
    for (int q = 0; q < 6; q++) {
      unsigned hb, lb;
      split2(vals[q], hb, lb);
      ph[q * 32 + j] = (short)hb;
      pl[q * 32 + j] = (short)lb;
    }
    return;
  }

  if (blk < 3584) {
    const int i = (blk - 512) * 256 + t;
    const float4 v = ((const float4*)x)[i];
    unsigned h0, l0, h1, l1, h2, l2, h3, l3;
    split2(v.x, h0, l0); split2(v.y, h1, l1); split2(v.z, h2, l2); split2(v.w, h3, l3);
    *(uint2*)&xh[(size_t)i * 4] = make_uint2(h0 | (h1 << 16), h2 | (h3 << 16));
    *(uint2*)&xl[(size_t)i * 4] = make_uint2(l0 | (l1 << 16), l2 | (l3 << 16));
    return;
  }

  const float* src; short* dh; short* dl; int R, C, local;
  if (blk < 3968)      { local = blk - 3584; src = Wq;   dh = wqkvh;               dl = wqkvl;               R = DIMM; C = HD; }
  else if (blk < 4352) { local = blk - 3968; src = Wk;   dh = wqkvh + 512 * DIMM;  dl = wqkvl + 512 * DIMM;  R = DIMM; C = HD; }
  else if (blk < 4736) { local = blk - 4352; src = Wv;   dh = wqkvh + 1024 * DIMM; dl = wqkvl + 1024 * DIMM; R = DIMM; C = HD; }
  else if (blk < 5120) { local = blk - 4736; src = Wout; dh = woh;  dl = wol;  R = HD;  C = DIMM; }
  else                 { local = blk - 5120; src = Wrel; dh = wrh;  dl = wrl;  R = 192; C = HD; }
  const int ctiles = C / 32;
  const int c0 = (local % ctiles) * 32, r0 = (local / ctiles) * 32;
  {
    const int lr = t >> 3, lc = (t & 7) * 4;
    const float4 v = *(const float4*)&src[(size_t)(r0 + lr) * C + c0 + lc];
    tile[lr][lc] = v.x; tile[lr][lc + 1] = v.y; tile[lr][lc + 2] = v.z; tile[lr][lc + 3] = v.w;
  }
  __syncthreads();
  const int nn = t >> 3, kb = (t & 7) * 4;
  unsigned hb[4], lb[4];
#pragma unroll
  for (int e = 0; e < 4; e++) split2(tile[kb + e][nn], hb[e], lb[e]);
  const size_t o = (size_t)(c0 + nn) * R + r0 + kb;
  *(uint2*)&dh[o] = make_uint2(hb[0] | (hb[1] << 16), hb[2] | (hb[3] << 16));
  *(uint2*)&dl[o] = make_uint2(lb[0] | (lb[1] << 16), lb[2] | (lb[3] << 16));
}

// ---------------- 2. unified qkv+relk GEMM, async global_load_lds staging ----------------
// grid 512: [0,384)=qkv (K=768), [384,512)=relk (K=192). 128x128 tile, BK=32.
// V epilogue writes V^T [bh][d][s] with per-64-chunk col swizzle s ^= ((d&7)<<3);
// relk epilogue writes d ^= ((m&7)<<3). Both consumed by attn (rule #21:
// pre-swizzled-global + swizzled LDS read, linear LDS via cp16).
__global__ __launch_bounds__(256) void gemm_qr(
    const short* __restrict__ xh, const short* __restrict__ xl,
    const short* __restrict__ wqkvh, const short* __restrict__ wqkvl,
    const short* __restrict__ eh, const short* __restrict__ el,
    const short* __restrict__ wrh, const short* __restrict__ wrl,
    const float* __restrict__ cb, const float* __restrict__ pb,
    bf16* __restrict__ oq, bf16* __restrict__ oqp,
    bf16* __restrict__ ok, short* __restrict__ vtw,
    bf16* __restrict__ relk) {
  __shared__ short AsH[128][32];
  __shared__ short AsL[128][32];
  __shared__ short BsH[128][32];
  __shared__ short BsL[128][32];

  const int bx = blockIdx.x;
  const bool isq = bx < 384;
  const int lbx = isq ? bx : bx - 384;
  const int mt = lbx & 31, ntile = lbx >> 5;
  const int m0 = mt * 128, n0 = ntile * 128;
  const int KD = isq ? DIMM : 192;
  const short* Ah = isq ? xh : eh;
  const short* Al = isq ? xl : el;
  const short* Bh = isq ? wqkvh : wrh;
  const short* Bl = isq ? wqkvl : wrl;

  const int t = threadIdx.x, lane = t & 63, w = t >> 6;
  const int quad = lane >> 4, l15 = lane & 15;
  const int wm = (w >> 1) * 64, wn = (w & 1) * 64;

  const int srow = w * 32 + (lane >> 2);   // + c*16
  const int skof = (lane & 3) * 8;         // shorts within 64B row

  f32x4 acc[4][4];
#pragma unroll
  for (int i = 0; i < 4; i++)
#pragma unroll
    for (int j = 0; j < 4; j++) acc[i][j] = (f32x4){0.f, 0.f, 0.f, 0.f};

  for (int k0 = 0; k0 < KD; k0 += 32) {
    __syncthreads();
#pragma unroll
    for (int c = 0; c < 2; c++) {
      const size_t ra = (size_t)(m0 + srow + c * 16) * KD + k0 + skof;
      const size_t rb = (size_t)(n0 + srow + c * 16) * KD + k0 + skof;
      cp16(&Ah[ra], &AsH[w * 32 + c * 16][0]);
      cp16(&Al[ra], &AsL[w * 32 + c * 16][0]);
      cp16(&Bh[rb], &BsH[w * 32 + c * 16][0]);
      cp16(&Bl[rb], &BsL[w * 32 + c * 16][0]);
    }
    __syncthreads();   // drains vmcnt(0): async data landed

    short8 amh[4], aml[4], bnh[4], bnl[4];
#pragma unroll
    for (int i = 0; i < 4; i++) {
      amh[i] = *(const short8*)&AsH[wm + i * 16 + l15][quad * 8];
      aml[i] = *(const short8*)&AsL[wm + i * 16 + l15][quad * 8];
      bnh[i] = *(const short8*)&BsH[wn + i * 16 + l15][quad * 8];
      bnl[i] = *(const short8*)&BsL[wn + i * 16 + l15][quad * 8];
    }
#pragma unroll
    for (int i = 0; i < 4; i++) {
#pragma unroll
      for (int j = 0; j < 4; j++) {
        acc[i][j] = __builtin_amdgcn_mfma_f32_16x16x32_bf16(amh[i], bnh[j], acc[i][j], 0, 0, 0);
        acc[i][j] = __builtin_amdgcn_mfma_f32_16x16x32_bf16(amh[i], bnl[j], acc[i][j], 0, 0, 0);
        acc[i][j] = __builtin_amdgcn_mfma_f32_16x16x32_bf16(aml[i], bnh[j], acc[i][j], 0, 0, 0);
      }
    }
  }

  if (isq) {
    const int sel = ntile >> 2;   // 0=q,1=k,2=v
    if (sel == 2) {
      // V^T write, swizzled: s' = s ^ ((d&7)<<3) within the 64-aligned chunk.
      // s base is 4-aligned; XOR touches bits 3..5 -> uint2 stays contiguous.
#pragma unroll
      for (int i = 0; i < 4; i++) {
#pragma unroll
        for (int j = 0; j < 4; j++) {
          const int n = n0 + wn + j * 16 + l15;
          const int hd_ = n & 511, hh = hd_ >> 6, d = hd_ & 63;
          const int m = m0 + wm + i * 16 + quad * 4;
          const int b = m >> 11, s = m & 2047;
          const int s_swz = s ^ ((d & 7) << 3);
          const uint2 pk = make_uint2(
              f2bf(acc[i][j][0]) | (f2bf(acc[i][j][1]) << 16),
              f2bf(acc[i][j][2]) | (f2bf(acc[i][j][3]) << 16));
          *(uint2*)&vtw[(((size_t)(b * HEADS + hh) * DK + d) * SEQ) + s_swz] = pk;
        }
      }
    } else {
#pragma unroll
      for (int i = 0; i < 4; i++) {
#pragma unroll
        for (int j = 0; j < 4; j++) {
          const int n = n0 + wn + j * 16 + l15;
          const int hd_ = n & 511, hh = hd_ >> 6, d = hd_ & 63;
#pragma unroll
          for (int g = 0; g < 4; g++) {
            const int m = m0 + wm + i * 16 + quad * 4 + g;
            const int b = m >> 11, s = m & 2047;
            const size_t idx = (((size_t)(b * HEADS + hh) * SEQ) + s) * DK + d;
            const float v = acc[i][j][g];
            if (sel == 0) {
              const float sv = v * 0.125f;   // dk^-0.5
              oq[idx]  = __float2bfloat16(sv + cb[hh * DK + d]);
              oqp[idx] = __float2bfloat16(sv + pb[hh * DK + d]);
            } else {
              ok[idx] = __float2bfloat16(v);
            }
          }
        }
      }
    }
  } else {
    // relk write, swizzled: d' = d ^ ((m&7)<<3)
#pragma unroll
    for (int i = 0; i < 4; i++) {
#pragma unroll
      for (int j = 0; j < 4; j++) {
        const int n = n0 + wn + j * 16 + l15;
        const int hh = n >> 6, d = n & 63;
#pragma unroll
        for (int g = 0; g < 4; g++) {
          const int m = m0 + wm + i * 16 + quad * 4 + g;
          if (m < NPOS)
            relk[((size_t)hh * NPOS + m) * DK + (d ^ ((m & 7) << 3))] =
                __float2bfloat16(acc[i][j][g]);
        }
      }
    }
  }
}

// ---------------- 3. out-projection GEMM, async staging ----------------
__global__ __launch_bounds__(256) void out_gemm(
    const short* __restrict__ Ahp,
    const short* __restrict__ Bhp, const short* __restrict__ Blp,
    const float* __restrict__ bias, float* __restrict__ ofp) {
  __shared__ short AsH[128][32];
  __shared__ short BsH[128][32];
  __shared__ short BsL[128][32];

  const int t = threadIdx.x, lane = t & 63, w = t >> 6;
  const int quad = lane >> 4, l15 = lane & 15;
  const int wm = (w >> 1) * 64, wn = (w & 1) * 64;
  const int m0 = blockIdx.x * 128, n0 = blockIdx.y * 128;
  const int srow = w * 32 + (lane >> 2);
  const int skof = (lane & 3) * 8;

  f32x4 acc[4][4];
#pragma unroll
  for (int i = 0; i < 4; i++)
#pragma unroll
    for (int j = 0; j < 4; j++) acc[i][j] = (f32x4){0.f, 0.f, 0.f, 0.f};

  for (int k0 = 0; k0 < HD; k0 += 32) {
    __syncthreads();
#pragma unroll
    for (int c = 0; c < 2; c++) {
      const size_t ra = (size_t)(m0 + srow + c * 16) * HD + k0 + skof;
      const size_t rb = (size_t)(n0 + srow + c * 16) * HD + k0 + skof;
      cp16(&Ahp[ra], &AsH[w * 32 + c * 16][0]);
      cp16(&Bhp[rb], &BsH[w * 32 + c * 16][0]);
      cp16(&Blp[rb], &BsL[w * 32 + c * 16][0]);
    }
    __syncthreads();

    short8 amh[4], bnh[4], bnl[4];
#pragma unroll
    for (int i = 0; i < 4; i++) {
      amh[i] = *(const short8*)&AsH[wm + i * 16 + l15][quad * 8];
      bnh[i] = *(const short8*)&BsH[wn + i * 16 + l15][quad * 8];
      bnl[i] = *(const short8*)&BsL[wn + i * 16 + l15][quad * 8];
    }
#pragma unroll
    for (int i = 0; i < 4; i++) {
#pragma unroll
      for (int j = 0; j < 4; j++) {
        acc[i][j] = __builtin_amdgcn_mfma_f32_16x16x32_bf16(amh[i], bnh[j], acc[i][j], 0, 0, 0);
        acc[i][j] = __builtin_amdgcn_mfma_f32_16x16x32_bf16(amh[i], bnl[j], acc[i][j], 0, 0, 0);
      }
    }
  }

#pragma unroll
  for (int i = 0; i < 4; i++) {
#pragma unroll
    for (int j = 0; j < 4; j++) {
      const int n = n0 + wn + j * 16 + l15;
      const float bv = bias[n];
#pragma unroll
      for (int g = 0; g < 4; g++) {
        const int m = m0 + wm + i * 16 + quad * 4 + g;
        ofp[(size_t)m * DIMM + n] = acc[i][j][g] + bv;
      }
    }
  }
}

// ---------------- 4. attention: 2-chunk rel ring + V cp16 dbuf, LDS = 40960 ----------------
// R7 lesson (2nd confirmation of R1): rel must stay in LDS — direct-global rel
// sits in the serial softmax chain and exposes L2 latency per window. R6 base
// (87us) with its two defects fixed at equal LDS:
//  - V^T dbuf via conflict-free cp16 (R7's STAGEV measured 0 conflicts) replaces
//    R6's reg->LDS ds_write (1.05M conflicts).
//  - rel ring 3->2 chunks: tile jt reads rows [j0+16, j0+128) = exactly 2 aligned
//    64-row chunks; slot = row & 127 (jb % 128 == 0), no mod-192. Prefetch of
//    rows [j0+128, j0+192) overwrites slots this tile already read -> issued
//    after the post-softmax barrier (C). 2 barriers/tile, both with >=PV-phase
//    of cp16 hiding. LDS 16384 + 16384 + 8192 = 40960 -> 4 blocks/CU.
__global__ __launch_bounds__(256) void attn_mfma4(
    const short* __restrict__ qc, const short* __restrict__ qp,
    const short* __restrict__ kg, const short* __restrict__ vt,
    const short* __restrict__ relk,
    float* __restrict__ Op, float* __restrict__ Lp) {
  __shared__ __align__(16) short RelR[128 * 64];     // 2-chunk rel ring, slot = row & 127
  __shared__ __align__(16) short VtB[2][64 * 64];    // V^T tile, double-buffered (cp16)
  __shared__ __align__(16) short Pw[4][16][64];      // per-wave P, XOR-swizzled

  const int bid = blockIdx.x;
  const int swz = (bid & 7) * 128 + (bid >> 3);   // bijective: 1024 % 8 == 0
  const int i0  = (swz & 31) * 64;
  const int bh  = (swz >> 5) & 15;
  const int z   = swz >> 9;
  const int h   = bh & 7;
  const int jb  = z * (SEQ / 2);

  const int t    = threadIdx.x;
  const int lane = t & 63;
  const int w    = t >> 6;
  const int quad = lane >> 4;
  const int l15  = lane & 15;
  const int x    = (l15 & 7) << 3;      // swizzle key (shorts)

  short8 qcA[2], qpA[2];
  {
    const size_t qrow = ((size_t)bh * SEQ + i0 + w * 16 + l15) * DK + quad * 8;
    qcA[0] = *(const short8*)(qc + qrow);
    qcA[1] = *(const short8*)(qc + qrow + 32);
    qpA[0] = *(const short8*)(qp + qrow);
    qpA[1] = *(const short8*)(qp + qrow + 32);
  }

  int idxg[4]; bool selg[4];
#pragma unroll
  for (int g = 0; g < 4; g++) {
    const int r = quad * 4 + g;
    idxg[g] = (((lane & 48) | ((l15 + 15 - r) & 15)) << 2);
    selg[g] = (l15 <= r);
  }

  short8 ones8;
#pragma unroll
  for (int e = 0; e < 8; e++) ones8[e] = (short)0x3F80;   // bf16 1.0

  f32x4 oacc[4];
#pragma unroll
  for (int dt = 0; dt < 4; dt++) oacc[dt] = (f32x4){0.f, 0.f, 0.f, 0.f};
  f32x4 lacc = (f32x4){0.f, 0.f, 0.f, 0.f};

  const short* kbase = kg + (size_t)bh * SEQ * DK;
  const short* vbase = vt + (size_t)bh * DK * SEQ;
  // rel rows indexed as (j - i0 + 1984) + offset; fold head base + (1984 - i0).
  const short* rbase = relk + ((size_t)(h * NPOS + 1984 - i0)) * DK;

  const int rb_w = 48 - 16 * w;

  // stage V^T tile at j0n into buffer nxt: 8 cp16 per block, 2 per wave (conflict-free)
  auto STAGEV = [&](int nxt, int j0n) {
#pragma unroll
    for (int cc = 0; cc < 2; cc++) {
      const int c = w * 2 + cc;
      cp16(vbase + (size_t)(c * 8 + (lane >> 3)) * SEQ + j0n + (lane & 7) * 8,
           &VtB[nxt][c * 512]);
    }
  };

  // ---- prologue ----
  // rel slots 16..127 = rows jb+16..jb+127 (14 cp16, wave-split)
#pragma unroll
  for (int cc = 0; cc < 4; cc++) {
    const int c = w + cc * 4;
    if (c < 14)
      cp16(rbase + (size_t)(jb + 16) * DK + c * 512 + lane * 8, &RelR[1024 + c * 512]);
  }
  STAGEV(0, jb);
  // carry init: bpermuted rel window 0 of tile 0 (direct global, swizzled cols)
  f32x4 bpp_carry;
  {
    const short* rl = rbase + (size_t)(jb + rb_w + l15) * DK;
    short8 b0 = *(const short8*)(rl + ((quad * 8) ^ x));
    short8 b1 = *(const short8*)(rl + ((quad * 8 + 32) ^ x));
    f32x4 a = (f32x4){0.f, 0.f, 0.f, 0.f};
    a = __builtin_amdgcn_mfma_f32_16x16x32_bf16(qpA[0], b0, a, 0, 0, 0);
    a = __builtin_amdgcn_mfma_f32_16x16x32_bf16(qpA[1], b1, a, 0, 0, 0);
#pragma unroll
    for (int g = 0; g < 4; g++)
      bpp_carry[g] = __int_as_float(__builtin_amdgcn_ds_bpermute(idxg[g], __float_as_int(a[g])));
  }
  __syncthreads();   // (A0) prologue staging landed

  int cur = 0;
  for (int jt = 0; jt < 16; jt++) {
    const int j0 = jb + jt * 64;
    const int rowoff = (jt & 1) * 64;   // ring chunk parity for this tile's base

    // V prefetch for tile jt+1: rides under this whole tile's compute
    if (jt < 15) STAGEV(cur ^ 1, j0 + 64);

    // QK^T: K fragments direct from global (independent batch, latency-tolerant)
    f32x4 sacc[4];
#pragma unroll
    for (int nt = 0; nt < 4; nt++) {
      const short* kr = kbase + (size_t)(j0 + nt * 16 + l15) * DK + quad * 8;
      short8 b0 = *(const short8*)kr;
      short8 b1 = *(const short8*)(kr + 32);
      f32x4 a = (f32x4){0.f, 0.f, 0.f, 0.f};
      a = __builtin_amdgcn_mfma_f32_16x16x32_bf16(qcA[0], b0, a, 0, 0, 0);
      a = __builtin_amdgcn_mfma_f32_16x16x32_bf16(qcA[1], b1, a, 0, 0, 0);
      sacc[nt] = a;
    }

    f32x4 bpp = bpp_carry;

#pragma unroll
    for (int nt = 0; nt < 4; nt++) {
      f32x4 rcur;
      {
        // ring slot for global row j0+16+rb_w+nt*16+l15 (jb ≡ 0 mod 128)
        const int slot = (rowoff + 16 + rb_w + nt * 16 + l15) & 127;
        const short* rl = &RelR[slot * 64];
        short8 b0 = *(const short8*)(rl + ((quad * 8) ^ x));
        short8 b1 = *(const short8*)(rl + ((quad * 8 + 32) ^ x));
        f32x4 a = (f32x4){0.f, 0.f, 0.f, 0.f};
        a = __builtin_amdgcn_mfma_f32_16x16x32_bf16(qpA[0], b0, a, 0, 0, 0);
        a = __builtin_amdgcn_mfma_f32_16x16x32_bf16(qpA[1], b1, a, 0, 0, 0);
        rcur = a;
      }
      f32x4 bpc;
#pragma unroll
      for (int g = 0; g < 4; g++)
        bpc[g] = __int_as_float(__builtin_amdgcn_ds_bpermute(idxg[g], __float_as_int(rcur[g])));
#pragma unroll
      for (int g = 0; g < 4; g++) {
        const float relv = selg[g] ? bpp[g] : bpc[g];
        const float s = sacc[nt][g] + relv;
        const float p = __expf(s - 12.0f);
        const int prow = quad * 4 + g;
        Pw[w][prow][(nt * 16 + l15) ^ ((prow & 7) << 3)] = (short)f2bf(p);
      }
      bpp = bpc;
    }
    bpp_carry = bpp;   // window 4 of this tile == window 0 of the next

    __syncthreads();   // (C) all waves' ring reads done -> in-place overwrite safe

    // rel prefetch for tile jt+1: rows [j0+128, j0+192) -> slots [rowoff, rowoff+64)
    if (jt < 15) {
      const short* rsrc = rbase + (size_t)(j0 + 128) * DK;
#pragma unroll
      for (int cc = 0; cc < 2; cc++) {
        const int c = w * 2 + cc;
        cp16(rsrc + c * 512 + lane * 8, &RelR[rowoff * 64 + c * 512]);
      }
    }

    // PV: hides the ring prefetch; VtB[cur] staged last tile (drained at C/A)
#pragma unroll
    for (int ks = 0; ks < 2; ks++) {
      short8 pA = *(const short8*)&Pw[w][l15][(ks * 32 + quad * 8) ^ x];
      lacc = __builtin_amdgcn_mfma_f32_16x16x32_bf16(pA, ones8, lacc, 0, 0, 0);
#pragma unroll
      for (int dt = 0; dt < 4; dt++) {
        const short* vl = &VtB[cur][(dt * 16 + l15) * 64 + ((ks * 32 + quad * 8) ^ x)];
        short8 vB = *(const short8*)vl;
        oacc[dt] = __builtin_amdgcn_mfma_f32_16x16x32_bf16(pA, vB, oacc[dt], 0, 0, 0);
      }
    }

    cur ^= 1;
    __syncthreads();   // (A) drains both prefetches; protects V dbuf swap + ring reads
  }

  const size_t obase = ((size_t)(z * BH + bh) * SEQ + i0 + w * 16);
#pragma unroll
  for (int g = 0; g < 4; g++) {
    const int r = quad * 4 + g;
#pragma unroll
    for (int dt = 0; dt < 4; dt++)
      Op[(obase + r) * DK + dt * 16 + l15] = oacc[dt][g];
    if (l15 == 0) Lp[obase + r] = lacc[g];
  }
}

// ---------------- 5. merge halves -> oh bf16 ----------------
__global__ void merge_kernel(const float* __restrict__ Op, const float* __restrict__ Lp,
                             bf16* __restrict__ oh) {
  const int gid = blockIdx.x * 256 + threadIdx.x;
  const int m = gid >> 7;
  const int n0 = (gid & 127) * 4;
  const int b = m >> 11, s = m & 2047;
  const int hh = n0 >> 6, d0 = n0 & 63;
  const int bh = b * HEADS + hh;
  const float l = Lp[(size_t)bh * SEQ + s] + Lp[((size_t)BH + bh) * SEQ + s];
  const float inv = 1.0f / l;
  const float4 o0 = *(const float4*)&Op[((size_t)bh * SEQ + s) * DK + d0];
  const float4 o1 = *(const float4*)&Op[(((size_t)BH + bh) * SEQ + s) * DK + d0];
  *(uint2*)&oh[(size_t)m * HD + n0] = make_uint2(
      f2bf((o0.x + o1.x) * inv) | (f2bf((o0.y + o1.y) * inv) << 16),
      f2bf((o0.z + o1.z) * inv) | (f2bf((o0.w + o1.w) * inv) << 16));
}

// ---------------- launch ----------------
extern "C" void kernel_launch(void* const* d_in, const int* in_sizes, int n_in,
                              void* d_out, int out_size, void* d_ws, size_t ws_size,
                              hipStream_t stream) {
  (void)in_sizes; (void)n_in; (void)out_size; (void)ws_size;
  const float* x    = (const float*)d_in[0];
  const float* Wq   = (const float*)d_in[1];
  const float* Wk   = (const float*)d_in[2];
  const float* Wv   = (const float*)d_in[3];
  const float* Wrel = (const float*)d_in[4];
  const float* Wout = (const float*)d_in[5];
  const float* bout = (const float*)d_in[6];
  const float* cb   = (const float*)d_in[7];
  const float* pb   = (const float*)d_in[8];
  float* out = (float*)d_out;

  char* ws = (char*)d_ws;
  bf16*  relk = (bf16*)(ws + OB_RELK);
  bf16*  qc   = (bf16*)(ws + OB_QC);
  bf16*  qp   = (bf16*)(ws + OB_QP);
  bf16*  kk   = (bf16*)(ws + OB_K);
  short* vt   = (short*)(ws + OB_V);    // V^T written directly by gemm_qr (swizzled)
  bf16*  oh   = (bf16*)(ws + OB_OH);
  float* Opb  = (float*)(ws + OB_OP);
  float* Lpb  = (float*)(ws + OB_LP);
  short* embh = (short*)(ws + OB_EMBH);
  short* embl = (short*)(ws + OB_EMBL);
  short* xh   = (short*)(ws + OB_XH);
  short* xl   = (short*)(ws + OB_XL);
  short* wqh  = (short*)(ws + OB_WQKVH);
  short* wql  = (short*)(ws + OB_WQKVL);
  short* woh  = (short*)(ws + OB_WOH);
  short* wol  = (short*)(ws + OB_WOL);
  short* wrh  = (short*)(ws + OB_WRH);
  short* wrl  = (short*)(ws + OB_WRL);

  hipLaunchKernelGGL(prep_all, dim3(5216), dim3(256), 0, stream,
                     x, Wq, Wk, Wv, Wout, Wrel,
                     embh, embl, xh, xl, wqh, wql, woh, wol, wrh, wrl);
  hipLaunchKernelGGL(gemm_qr, dim3(512), dim3(256), 0, stream,
                     xh, xl, wqh, wql, embh, embl, wrh, wrl,
                     cb, pb, qc, qp, kk, vt, relk);
  hipLaunchKernelGGL(attn_mfma4, dim3(1024), dim3(256), 0, stream,
                     (const short*)qc, (const short*)qp, (const short*)kk,
                     (const short*)vt, (const short*)relk, Opb, Lpb);
  hipLaunchKernelGGL(merge_kernel, dim3(ROWS * (HD / 4) / 256), dim3(256), 0, stream,
                     Opb, Lpb, oh);
  hipLaunchKernelGGL(out_gemm, dim3(32, 6), dim3(256), 0, stream,
                     (const short*)oh, woh, wol, bout, out);
}

// Round 10
// 215.083 us; speedup vs baseline: 1.2958x; 1.0386x over previous
//
#include <hip/hip_runtime.h>
#include <hip/hip_bf16.h>
#include <math.h>
#include <stdint.h>

typedef __hip_bfloat16 bf16;
typedef __attribute__((ext_vector_type(8))) short short8;  // 8 bf16 = 4 VGPRs
typedef __attribute__((ext_vector_type(4))) float f32x4;

#define SEQ   2048
#define NPOS  4095          // 2*SEQ-1
#define DIMM  768
#define HEADS 8
#define DK    64
#define HD    512           // HEADS*DK
#define BATCH 2
#define BH    16            // BATCH*HEADS
#define ROWS  4096          // BATCH*SEQ

// ---------------- workspace layout (BYTE offsets), ~44.4 MB ----------------
#define OB_RELK  ((size_t)0)                      // bf16 [8][4095][64], col-swizzled
#define OB_QC    ((size_t)4194304)
#define OB_QP    ((size_t)8388608)
#define OB_K     ((size_t)12582912)
#define OB_V     ((size_t)16777216)               // V^T [bh][64][2048], chunk-swizzled
#define OB_OH    ((size_t)20971520)               // bf16 [4096][512]
// aliased (disjoint lifetimes):
#define OB_EMBH  OB_OH                            // dead after gemm_qr
#define OB_EMBL  ((size_t)(OB_OH + 1572864))
#define OB_XH    ((size_t)25165824)               // dead after gemm_qr
#define OB_XL    ((size_t)31457280)
#define OB_WQKVH ((size_t)37748736)               // dead after gemm_qr
#define OB_WQKVL ((size_t)40108032)
#define OB_OP    ((size_t)25165824)               // f32 [2][16][2048][64] partial O
#define OB_LP    ((size_t)41943040)               // f32 [2][16][2048] partial l
#define OB_WOH   ((size_t)42467328)               // out-proj weights
#define OB_WOL   ((size_t)43253760)
#define OB_WRH   ((size_t)44040192)
#define OB_WRL   ((size_t)44236800)

// RNE float -> bf16 bits (finite inputs only)
__device__ __forceinline__ unsigned f2bf(float f) {
  unsigned u = __float_as_uint(f);
  return (u + 0x7fffu + ((u >> 16) & 1u)) >> 16;
}
__device__ __forceinline__ void split2(float v, unsigned& hb, unsigned& lb) {
  hb = f2bf(v);
  const float back = __uint_as_float(hb << 16);
  lb = f2bf(v - back);
}

// async global->LDS 16B copy (m97 pattern; CK-style addrspace casts).
// l must be wave-uniform; HW writes l + lane*16. g is per-lane.
__device__ __forceinline__ void cp16(const short* g, short* l) {
  __builtin_amdgcn_global_load_lds(
      (__attribute__((address_space(1))) void*)(uintptr_t)(g),
      (__attribute__((address_space(3))) void*)(uint32_t)(uintptr_t)(l),
      16, 0, 0);
}

// ---------------- 1. fused prep: pos_emb + conv_split + 5 transposes ----------------
__global__ __launch_bounds__(256) void prep_all(
    const float* __restrict__ x,
    const float* __restrict__ Wq, const float* __restrict__ Wk,
    const float* __restrict__ Wv, const float* __restrict__ Wout,
    const float* __restrict__ Wrel,
    short* __restrict__ eh, short* __restrict__ el,
    short* __restrict__ xh, short* __restrict__ xl,
    short* __restrict__ wqkvh, short* __restrict__ wqkvl,
    short* __restrict__ woh, short* __restrict__ wol,
    short* __restrict__ wrh, short* __restrict__ wrl) {
  __shared__ float tile[32][33];
  const int blk = blockIdx.x;
  const int t = threadIdx.x;

  if (blk < 512) {
    const int row = blk * 8 + (t >> 5);
    const int j   = t & 31;
    if (row >= NPOS) {
      for (int c = j; c < 192; c += 32) { eh[(size_t)row * 192 + c] = 0; el[(size_t)row * 192 + c] = 0; }
      return;
    }
    const float dist = (float)(row - (SEQ - 1));
    const float ad   = fabsf(dist);
    const float hl    = exp2f(3.0f + 8.0f * (float)j / 31.0f);
    const float f_exp = exp2f(-ad / hl);
    const float width = exp2f((float)(j + 1)) - 1.0f;
    const float f_cm  = (width > ad) ? 1.0f : 0.0f;
    float prob;
    if (ad > 0.0f) {
      const float c   = 4.0f * (float)((j + 1) * (j + 1));
      const float r   = (float)(j + 1) / 16.0f;
      const float lu  = (c - 1.0f) * logf(ad) - r * ad;
      const float ln_ = lgammaf(c) - c * logf(r);
      prob = expf(lu - ln_) + 1e-8f;
    } else {
      prob = 1e-8f;
    }
    float mx = prob;
    for (int off = 16; off; off >>= 1) mx = fmaxf(mx, __shfl_xor(mx, off, 32));
    const float f_g = prob / mx;
    const float s = (dist > 0.f) ? 1.f : ((dist < 0.f) ? -1.f : 0.f);
    const float vals[6] = {f_exp, f_cm, f_g, s * f_exp, s * f_cm, s * f_g};
    short* ph = eh + (size_t)row * 192;
    short* pl = el + (size_t)row * 192;
#pragma unroll
    for (int q = 0; q < 6; q++) {
      unsigned hb, lb;
      split2(vals[q], hb, lb);
      ph[q * 32 + j] = (short)hb;
      pl[q * 32 + j] = (short)lb;
    }
    return;
  }

  if (blk < 3584) {
    const int i = (blk - 512) * 256 + t;
    const float4 v = ((const float4*)x)[i];
    unsigned h0, l0, h1, l1, h2, l2, h3, l3;
    split2(v.x, h0, l0); split2(v.y, h1, l1); split2(v.z, h2, l2); split2(v.w, h3, l3);
    *(uint2*)&xh[(size_t)i * 4] = make_uint2(h0 | (h1 << 16), h2 | (h3 << 16));
    *(uint2*)&xl[(size_t)i * 4] = make_uint2(l0 | (l1 << 16), l2 | (l3 << 16));
    return;
  }

  const float* src; short* dh; short* dl; int R, C, local;
  if (blk < 3968)      { local = blk - 3584; src = Wq;   dh = wqkvh;               dl = wqkvl;               R = DIMM; C = HD; }
  else if (blk < 4352) { local = blk - 3968; src = Wk;   dh = wqkvh + 512 * DIMM;  dl = wqkvl + 512 * DIMM;  R = DIMM; C = HD; }
  else if (blk < 4736) { local = blk - 4352; src = Wv;   dh = wqkvh + 1024 * DIMM; dl = wqkvl + 1024 * DIMM; R = DIMM; C = HD; }
  else if (blk < 5120) { local = blk - 4736; src = Wout; dh = woh;  dl = wol;  R = HD;  C = DIMM; }
  else                 { local = blk - 5120; src = Wrel; dh = wrh;  dl = wrl;  R = 192; C = HD; }
  const int ctiles = C / 32;
  const int c0 = (local % ctiles) * 32, r0 = (local / ctiles) * 32;
  {
    const int lr = t >> 3, lc = (t & 7) * 4;
    const float4 v = *(const float4*)&src[(size_t)(r0 + lr) * C + c0 + lc];
    tile[lr][lc] = v.x; tile[lr][lc + 1] = v.y; tile[lr][lc + 2] = v.z; tile[lr][lc + 3] = v.w;
  }
  __syncthreads();
  const int nn = t >> 3, kb = (t & 7) * 4;
  unsigned hb[4], lb[4];
#pragma unroll
  for (int e = 0; e < 4; e++) split2(tile[kb + e][nn], hb[e], lb[e]);
  const size_t o = (size_t)(c0 + nn) * R + r0 + kb;
  *(uint2*)&dh[o] = make_uint2(hb[0] | (hb[1] << 16), hb[2] | (hb[3] << 16));
  *(uint2*)&dl[o] = make_uint2(lb[0] | (lb[1] << 16), lb[2] | (lb[3] << 16));
}

// ---------------- 2. unified qkv+relk GEMM, double-buffered cp16 staging ----------------
// R10: port the R9-proven attn pattern (issue next K-step's cp16 BEFORE computing
// the current one; single barrier per step). LDS 32KB -> 64KB: capacity
// floor(163840/65536)=2 == grid residency (512 blocks / 256 CU), no occupancy
// loss; barrier count halves and every drain has ~48 MFMA + 16 ds_read of cover.
__global__ __launch_bounds__(256) void gemm_qr(
    const short* __restrict__ xh, const short* __restrict__ xl,
    const short* __restrict__ wqkvh, const short* __restrict__ wqkvl,
    const short* __restrict__ eh, const short* __restrict__ el,
    const short* __restrict__ wrh, const short* __restrict__ wrl,
    const float* __restrict__ cb, const float* __restrict__ pb,
    bf16* __restrict__ oq, bf16* __restrict__ oqp,
    bf16* __restrict__ ok, short* __restrict__ vtw,
    bf16* __restrict__ relk) {
  __shared__ short AsH[2][128][32];
  __shared__ short AsL[2][128][32];
  __shared__ short BsH[2][128][32];
  __shared__ short BsL[2][128][32];

  const int bx = blockIdx.x;
  const bool isq = bx < 384;
  const int lbx = isq ? bx : bx - 384;
  const int mt = lbx & 31, ntile = lbx >> 5;
  const int m0 = mt * 128, n0 = ntile * 128;
  const int KD = isq ? DIMM : 192;
  const short* Ah = isq ? xh : eh;
  const short* Al = isq ? xl : el;
  const short* Bh = isq ? wqkvh : wrh;
  const short* Bl = isq ? wqkvl : wrl;

  const int t = threadIdx.x, lane = t & 63, w = t >> 6;
  const int quad = lane >> 4, l15 = lane & 15;
  const int wm = (w >> 1) * 64, wn = (w & 1) * 64;

  const int srow = w * 32 + (lane >> 2);   // + c*16
  const int skof = (lane & 3) * 8;         // shorts within 64B row

  auto STAGE = [&](int bb, int k0) {
#pragma unroll
    for (int c = 0; c < 2; c++) {
      const size_t ra = (size_t)(m0 + srow + c * 16) * KD + k0 + skof;
      const size_t rb = (size_t)(n0 + srow + c * 16) * KD + k0 + skof;
      cp16(&Ah[ra], &AsH[bb][w * 32 + c * 16][0]);
      cp16(&Al[ra], &AsL[bb][w * 32 + c * 16][0]);
      cp16(&Bh[rb], &BsH[bb][w * 32 + c * 16][0]);
      cp16(&Bl[rb], &BsL[bb][w * 32 + c * 16][0]);
    }
  };

  f32x4 acc[4][4];
#pragma unroll
  for (int i = 0; i < 4; i++)
#pragma unroll
    for (int j = 0; j < 4; j++) acc[i][j] = (f32x4){0.f, 0.f, 0.f, 0.f};

  STAGE(0, 0);
  __syncthreads();   // tile 0 landed (vmcnt drain)

  int bb = 0;
  for (int k0 = 0; k0 < KD; k0 += 32) {
    if (k0 + 32 < KD) STAGE(bb ^ 1, k0 + 32);   // rides under this step's compute

    short8 amh[4], aml[4], bnh[4], bnl[4];
#pragma unroll
    for (int i = 0; i < 4; i++) {
      amh[i] = *(const short8*)&AsH[bb][wm + i * 16 + l15][quad * 8];
      aml[i] = *(const short8*)&AsL[bb][wm + i * 16 + l15][quad * 8];
      bnh[i] = *(const short8*)&BsH[bb][wn + i * 16 + l15][quad * 8];
      bnl[i] = *(const short8*)&BsL[bb][wn + i * 16 + l15][quad * 8];
    }
#pragma unroll
    for (int i = 0; i < 4; i++) {
#pragma unroll
      for (int j = 0; j < 4; j++) {
        acc[i][j] = __builtin_amdgcn_mfma_f32_16x16x32_bf16(amh[i], bnh[j], acc[i][j], 0, 0, 0);
        acc[i][j] = __builtin_amdgcn_mfma_f32_16x16x32_bf16(amh[i], bnl[j], acc[i][j], 0, 0, 0);
        acc[i][j] = __builtin_amdgcn_mfma_f32_16x16x32_bf16(aml[i], bnh[j], acc[i][j], 0, 0, 0);
      }
    }

    __syncthreads();   // drains prefetch (hidden under MFMAs); protects swap
    bb ^= 1;
  }

  if (isq) {
    const int sel = ntile >> 2;   // 0=q,1=k,2=v
    if (sel == 2) {
      // V^T write, swizzled: s' = s ^ ((d&7)<<3) within the 64-aligned chunk.
#pragma unroll
      for (int i = 0; i < 4; i++) {
#pragma unroll
        for (int j = 0; j < 4; j++) {
          const int n = n0 + wn + j * 16 + l15;
          const int hd_ = n & 511, hh = hd_ >> 6, d = hd_ & 63;
          const int m = m0 + wm + i * 16 + quad * 4;
          const int b = m >> 11, s = m & 2047;
          const int s_swz = s ^ ((d & 7) << 3);
          const uint2 pk = make_uint2(
              f2bf(acc[i][j][0]) | (f2bf(acc[i][j][1]) << 16),
              f2bf(acc[i][j][2]) | (f2bf(acc[i][j][3]) << 16));
          *(uint2*)&vtw[(((size_t)(b * HEADS + hh) * DK + d) * SEQ) + s_swz] = pk;
        }
      }
    } else {
#pragma unroll
      for (int i = 0; i < 4; i++) {
#pragma unroll
        for (int j = 0; j < 4; j++) {
          const int n = n0 + wn + j * 16 + l15;
          const int hd_ = n & 511, hh = hd_ >> 6, d = hd_ & 63;
#pragma unroll
          for (int g = 0; g < 4; g++) {
            const int m = m0 + wm + i * 16 + quad * 4 + g;
            const int b = m >> 11, s = m & 2047;
            const size_t idx = (((size_t)(b * HEADS + hh) * SEQ) + s) * DK + d;
            const float v = acc[i][j][g];
            if (sel == 0) {
              const float sv = v * 0.125f;   // dk^-0.5
              oq[idx]  = __float2bfloat16(sv + cb[hh * DK + d]);
              oqp[idx] = __float2bfloat16(sv + pb[hh * DK + d]);
            } else {
              ok[idx] = __float2bfloat16(v);
            }
          }
        }
      }
    }
  } else {
    // relk write, swizzled: d' = d ^ ((m&7)<<3)
#pragma unroll
    for (int i = 0; i < 4; i++) {
#pragma unroll
      for (int j = 0; j < 4; j++) {
        const int n = n0 + wn + j * 16 + l15;
        const int hh = n >> 6, d = n & 63;
#pragma unroll
        for (int g = 0; g < 4; g++) {
          const int m = m0 + wm + i * 16 + quad * 4 + g;
          if (m < NPOS)
            relk[((size_t)hh * NPOS + m) * DK + (d ^ ((m & 7) << 3))] =
                __float2bfloat16(acc[i][j][g]);
        }
      }
    }
  }
}

// ---------------- 3. out-projection GEMM, double-buffered cp16 staging ----------------
__global__ __launch_bounds__(256) void out_gemm(
    const short* __restrict__ Ahp,
    const short* __restrict__ Bhp, const short* __restrict__ Blp,
    const float* __restrict__ bias, float* __restrict__ ofp) {
  __shared__ short AsH[2][128][32];
  __shared__ short BsH[2][128][32];
  __shared__ short BsL[2][128][32];

  const int t = threadIdx.x, lane = t & 63, w = t >> 6;
  const int quad = lane >> 4, l15 = lane & 15;
  const int wm = (w >> 1) * 64, wn = (w & 1) * 64;
  const int m0 = blockIdx.x * 128, n0 = blockIdx.y * 128;
  const int srow = w * 32 + (lane >> 2);
  const int skof = (lane & 3) * 8;

  auto STAGE = [&](int bb, int k0) {
#pragma unroll
    for (int c = 0; c < 2; c++) {
      const size_t ra = (size_t)(m0 + srow + c * 16) * HD + k0 + skof;
      const size_t rb = (size_t)(n0 + srow + c * 16) * HD + k0 + skof;
      cp16(&Ahp[ra], &AsH[bb][w * 32 + c * 16][0]);
      cp16(&Bhp[rb], &BsH[bb][w * 32 + c * 16][0]);
      cp16(&Blp[rb], &BsL[bb][w * 32 + c * 16][0]);
    }
  };

  f32x4 acc[4][4];
#pragma unroll
  for (int i = 0; i < 4; i++)
#pragma unroll
    for (int j = 0; j < 4; j++) acc[i][j] = (f32x4){0.f, 0.f, 0.f, 0.f};

  STAGE(0, 0);
  __syncthreads();

  int bb = 0;
  for (int k0 = 0; k0 < HD; k0 += 32) {
    if (k0 + 32 < HD) STAGE(bb ^ 1, k0 + 32);

    short8 amh[4], bnh[4], bnl[4];
#pragma unroll
    for (int i = 0; i < 4; i++) {
      amh[i] = *(const short8*)&AsH[bb][wm + i * 16 + l15][quad * 8];
      bnh[i] = *(const short8*)&BsH[bb][wn + i * 16 + l15][quad * 8];
      bnl[i] = *(const short8*)&BsL[bb][wn + i * 16 + l15][quad * 8];
    }
#pragma unroll
    for (int i = 0; i < 4; i++) {
#pragma unroll
      for (int j = 0; j < 4; j++) {
        acc[i][j] = __builtin_amdgcn_mfma_f32_16x16x32_bf16(amh[i], bnh[j], acc[i][j], 0, 0, 0);
        acc[i][j] = __builtin_amdgcn_mfma_f32_16x16x32_bf16(amh[i], bnl[j], acc[i][j], 0, 0, 0);
      }
    }

    __syncthreads();
    bb ^= 1;
  }

#pragma unroll
  for (int i = 0; i < 4; i++) {
#pragma unroll
    for (int j = 0; j < 4; j++) {
      const int n = n0 + wn + j * 16 + l15;
      const float bv = bias[n];
#pragma unroll
      for (int g = 0; g < 4; g++) {
        const int m = m0 + wm + i * 16 + quad * 4 + g;
        ofp[(size_t)m * DIMM + n] = acc[i][j][g] + bv;
      }
    }
  }
}

// ---------------- 4. attention: 2-chunk rel ring + V cp16 dbuf, LDS = 40960 (R9, unchanged) ----------------
__global__ __launch_bounds__(256) void attn_mfma4(
    const short* __restrict__ qc, const short* __restrict__ qp,
    const short* __restrict__ kg, const short* __restrict__ vt,
    const short* __restrict__ relk,
    float* __restrict__ Op, float* __restrict__ Lp) {
  __shared__ __align__(16) short RelR[128 * 64];     // 2-chunk rel ring, slot = row & 127
  __shared__ __align__(16) short VtB[2][64 * 64];    // V^T tile, double-buffered (cp16)
  __shared__ __align__(16) short Pw[4][16][64];      // per-wave P, XOR-swizzled

  const int bid = blockIdx.x;
  const int swz = (bid & 7) * 128 + (bid >> 3);   // bijective: 1024 % 8 == 0
  const int i0  = (swz & 31) * 64;
  const int bh  = (swz >> 5) & 15;
  const int z   = swz >> 9;
  const int h   = bh & 7;
  const int jb  = z * (SEQ / 2);

  const int t    = threadIdx.x;
  const int lane = t & 63;
  const int w    = t >> 6;
  const int quad = lane >> 4;
  const int l15  = lane & 15;
  const int x    = (l15 & 7) << 3;      // swizzle key (shorts)

  short8 qcA[2], qpA[2];
  {
    const size_t qrow = ((size_t)bh * SEQ + i0 + w * 16 + l15) * DK + quad * 8;
    qcA[0] = *(const short8*)(qc + qrow);
    qcA[1] = *(const short8*)(qc + qrow + 32);
    qpA[0] = *(const short8*)(qp + qrow);
    qpA[1] = *(const short8*)(qp + qrow + 32);
  }

  int idxg[4]; bool selg[4];
#pragma unroll
  for (int g = 0; g < 4; g++) {
    const int r = quad * 4 + g;
    idxg[g] = (((lane & 48) | ((l15 + 15 - r) & 15)) << 2);
    selg[g] = (l15 <= r);
  }

  short8 ones8;
#pragma unroll
  for (int e = 0; e < 8; e++) ones8[e] = (short)0x3F80;   // bf16 1.0

  f32x4 oacc[4];
#pragma unroll
  for (int dt = 0; dt < 4; dt++) oacc[dt] = (f32x4){0.f, 0.f, 0.f, 0.f};
  f32x4 lacc = (f32x4){0.f, 0.f, 0.f, 0.f};

  const short* kbase = kg + (size_t)bh * SEQ * DK;
  const short* vbase = vt + (size_t)bh * DK * SEQ;
  // rel rows indexed as (j - i0 + 1984) + offset; fold head base + (1984 - i0).
  const short* rbase = relk + ((size_t)(h * NPOS + 1984 - i0)) * DK;

  const int rb_w = 48 - 16 * w;

  // stage V^T tile at j0n into buffer nxt: 8 cp16 per block, 2 per wave (conflict-free)
  auto STAGEV = [&](int nxt, int j0n) {
#pragma unroll
    for (int cc = 0; cc < 2; cc++) {
      const int c = w * 2 + cc;
      cp16(vbase + (size_t)(c * 8 + (lane >> 3)) * SEQ + j0n + (lane & 7) * 8,
           &VtB[nxt][c * 512]);
    }
  };

  // ---- prologue ----
  // rel slots 16..127 = rows jb+16..jb+127 (14 cp16, wave-split)
#pragma unroll
  for (int cc = 0; cc < 4; cc++) {
    const int c = w + cc * 4;
    if (c < 14)
      cp16(rbase + (size_t)(jb + 16) * DK + c * 512 + lane * 8, &RelR[1024 + c * 512]);
  }
  STAGEV(0, jb);
  // carry init: bpermuted rel window 0 of tile 0 (direct global, swizzled cols)
  f32x4 bpp_carry;
  {
    const short* rl = rbase + (size_t)(jb + rb_w + l15) * DK;
    short8 b0 = *(const short8*)(rl + ((quad * 8) ^ x));
    short8 b1 = *(const short8*)(rl + ((quad * 8 + 32) ^ x));
    f32x4 a = (f32x4){0.f, 0.f, 0.f, 0.f};
    a = __builtin_amdgcn_mfma_f32_16x16x32_bf16(qpA[0], b0, a, 0, 0, 0);
    a = __builtin_amdgcn_mfma_f32_16x16x32_bf16(qpA[1], b1, a, 0, 0, 0);
#pragma unroll
    for (int g = 0; g < 4; g++)
      bpp_carry[g] = __int_as_float(__builtin_amdgcn_ds_bpermute(idxg[g], __float_as_int(a[g])));
  }
  __syncthreads();   // (A0) prologue staging landed

  int cur = 0;
  for (int jt = 0; jt < 16; jt++) {
    const int j0 = jb + jt * 64;
    const int rowoff = (jt & 1) * 64;   // ring chunk parity for this tile's base

    // V prefetch for tile jt+1: rides under this whole tile's compute
    if (jt < 15) STAGEV(cur ^ 1, j0 + 64);

    // QK^T: K fragments direct from global (independent batch, latency-tolerant)
    f32x4 sacc[4];
#pragma unroll
    for (int nt = 0; nt < 4; nt++) {
      const short* kr = kbase + (size_t)(j0 + nt * 16 + l15) * DK + quad * 8;
      short8 b0 = *(const short8*)kr;
      short8 b1 = *(const short8*)(kr + 32);
      f32x4 a = (f32x4){0.f, 0.f, 0.f, 0.f};
      a = __builtin_amdgcn_mfma_f32_16x16x32_bf16(qcA[0], b0, a, 0, 0, 0);
      a = __builtin_amdgcn_mfma_f32_16x16x32_bf16(qcA[1], b1, a, 0, 0, 0);
      sacc[nt] = a;
    }

    f32x4 bpp = bpp_carry;

#pragma unroll
    for (int nt = 0; nt < 4; nt++) {
      f32x4 rcur;
      {
        // ring slot for global row j0+16+rb_w+nt*16+l15 (jb ≡ 0 mod 128)
        const int slot = (rowoff + 16 + rb_w + nt * 16 + l15) & 127;
        const short* rl = &RelR[slot * 64];
        short8 b0 = *(const short8*)(rl + ((quad * 8) ^ x));
        short8 b1 = *(const short8*)(rl + ((quad * 8 + 32) ^ x));
        f32x4 a = (f32x4){0.f, 0.f, 0.f, 0.f};
        a = __builtin_amdgcn_mfma_f32_16x16x32_bf16(qpA[0], b0, a, 0, 0, 0);
        a = __builtin_amdgcn_mfma_f32_16x16x32_bf16(qpA[1], b1, a, 0, 0, 0);
        rcur = a;
      }
      f32x4 bpc;
#pragma unroll
      for (int g = 0; g < 4; g++)
        bpc[g] = __int_as_float(__builtin_amdgcn_ds_bpermute(idxg[g], __float_as_int(rcur[g])));
#pragma unroll
      for (int g = 0; g < 4; g++) {
        const float relv = selg[g] ? bpp[g] : bpc[g];
        const float s = sacc[nt][g] + relv;
        const float p = __expf(s - 12.0f);
        const int prow = quad * 4 + g;
        Pw[w][prow][(nt * 16 + l15) ^ ((prow & 7) << 3)] = (short)f2bf(p);
      }
      bpp = bpc;
    }
    bpp_carry = bpp;   // window 4 of this tile == window 0 of the next

    __syncthreads();   // (C) all waves' ring reads done -> in-place overwrite safe

    // rel prefetch for tile jt+1: rows [j0+128, j0+192) -> slots [rowoff, rowoff+64)
    if (jt < 15) {
      const short* rsrc = rbase + (size_t)(j0 + 128) * DK;
#pragma unroll
      for (int cc = 0; cc < 2; cc++) {
        const int c = w * 2 + cc;
        cp16(rsrc + c * 512 + lane * 8, &RelR[rowoff * 64 + c * 512]);
      }
    }

    // PV: hides the ring prefetch; VtB[cur] staged last tile (drained at C/A)
#pragma unroll
    for (int ks = 0; ks < 2; ks++) {
      short8 pA = *(const short8*)&Pw[w][l15][(ks * 32 + quad * 8) ^ x];
      lacc = __builtin_amdgcn_mfma_f32_16x16x32_bf16(pA, ones8, lacc, 0, 0, 0);
#pragma unroll
      for (int dt = 0; dt < 4; dt++) {
        const short* vl = &VtB[cur][(dt * 16 + l15) * 64 + ((ks * 32 + quad * 8) ^ x)];
        short8 vB = *(const short8*)vl;
        oacc[dt] = __builtin_amdgcn_mfma_f32_16x16x32_bf16(pA, vB, oacc[dt], 0, 0, 0);
      }
    }

    cur ^= 1;
    __syncthreads();   // (A) drains both prefetches; protects V dbuf swap + ring reads
  }

  const size_t obase = ((size_t)(z * BH + bh) * SEQ + i0 + w * 16);
#pragma unroll
  for (int g = 0; g < 4; g++) {
    const int r = quad * 4 + g;
#pragma unroll
    for (int dt = 0; dt < 4; dt++)
      Op[(obase + r) * DK + dt * 16 + l15] = oacc[dt][g];
    if (l15 == 0) Lp[obase + r] = lacc[g];
  }
}

// ---------------- 5. merge halves -> oh bf16 ----------------
__global__ void merge_kernel(const float* __restrict__ Op, const float* __restrict__ Lp,
                             bf16* __restrict__ oh) {
  const int gid = blockIdx.x * 256 + threadIdx.x;
  const int m = gid >> 7;
  const int n0 = (gid & 127) * 4;
  const int b = m >> 11, s = m & 2047;
  const int hh = n0 >> 6, d0 = n0 & 63;
  const int bh = b * HEADS + hh;
  const float l = Lp[(size_t)bh * SEQ + s] + Lp[((size_t)BH + bh) * SEQ + s];
  const float inv = 1.0f / l;
  const float4 o0 = *(const float4*)&Op[((size_t)bh * SEQ + s) * DK + d0];
  const float4 o1 = *(const float4*)&Op[(((size_t)BH + bh) * SEQ + s) * DK + d0];
  *(uint2*)&oh[(size_t)m * HD + n0] = make_uint2(
      f2bf((o0.x + o1.x) * inv) | (f2bf((o0.y + o1.y) * inv) << 16),
      f2bf((o0.z + o1.z) * inv) | (f2bf((o0.w + o1.w) * inv) << 16));
}

// ---------------- launch ----------------
extern "C" void kernel_launch(void* const* d_in, const int* in_sizes, int n_in,
                              void* d_out, int out_size, void* d_ws, size_t ws_size,
                              hipStream_t stream) {
  (void)in_sizes; (void)n_in; (void)out_size; (void)ws_size;
  const float* x    = (const float*)d_in[0];
  const float* Wq   = (const float*)d_in[1];
  const float* Wk   = (const float*)d_in[2];
  const float* Wv   = (const float*)d_in[3];
  const float* Wrel = (const float*)d_in[4];
  const float* Wout = (const float*)d_in[5];
  const float* bout = (const float*)d_in[6];
  const float* cb   = (const float*)d_in[7];
  const float* pb   = (const float*)d_in[8];
  float* out = (float*)d_out;

  char* ws = (char*)d_ws;
  bf16*  relk = (bf16*)(ws + OB_RELK);
  bf16*  qc   = (bf16*)(ws + OB_QC);
  bf16*  qp   = (bf16*)(ws + OB_QP);
  bf16*  kk   = (bf16*)(ws + OB_K);
  short* vt   = (short*)(ws + OB_V);    // V^T written directly by gemm_qr (swizzled)
  bf16*  oh   = (bf16*)(ws + OB_OH);
  float* Opb  = (float*)(ws + OB_OP);
  float* Lpb  = (float*)(ws + OB_LP);
  short* embh = (short*)(ws + OB_EMBH);
  short* embl = (short*)(ws + OB_EMBL);
  short* xh   = (short*)(ws + OB_XH);
  short* xl   = (short*)(ws + OB_XL);
  short* wqh  = (short*)(ws + OB_WQKVH);
  short* wql  = (short*)(ws + OB_WQKVL);
  short* woh  = (short*)(ws + OB_WOH);
  short* wol  = (short*)(ws + OB_WOL);
  short* wrh  = (short*)(ws + OB_WRH);
  short* wrl  = (short*)(ws + OB_WRL);

  hipLaunchKernelGGL(prep_all, dim3(5216), dim3(256), 0, stream,
                     x, Wq, Wk, Wv, Wout, Wrel,
                     embh, embl, xh, xl, wqh, wql, woh, wol, wrh, wrl);
  hipLaunchKernelGGL(gemm_qr, dim3(512), dim3(256), 0, stream,
                     xh, xl, wqh, wql, embh, embl, wrh, wrl,
                     cb, pb, qc, qp, kk, vt, relk);
  hipLaunchKernelGGL(attn_mfma4, dim3(1024), dim3(256), 0, stream,
                     (const short*)qc, (const short*)qp, (const short*)kk,
                     (const short*)vt, (const short*)relk, Opb, Lpb);
  hipLaunchKernelGGL(merge_kernel, dim3(ROWS * (HD / 4) / 256), dim3(256), 0, stream,
                     Opb, Lpb, oh);
  hipLaunchKernelGGL(out_gemm, dim3(32, 6), dim3(256), 0, stream,
                     (const short*)oh, woh, wol, bout, out);
}

// Round 11
// 214.916 us; speedup vs baseline: 1.2968x; 1.0008x over previous
//
#include <hip/hip_runtime.h>
#include <hip/hip_bf16.h>
#include <math.h>
#include <stdint.h>

typedef __hip_bfloat16 bf16;
typedef __attribute__((ext_vector_type(8))) short short8;  // 8 bf16 = 4 VGPRs
typedef __attribute__((ext_vector_type(4))) float f32x4;

#define SEQ   2048
#define NPOS  4095          // 2*SEQ-1
#define DIMM  768
#define HEADS 8
#define DK    64
#define HD    512           // HEADS*DK
#define BATCH 2
#define BH    16            // BATCH*HEADS
#define ROWS  4096          // BATCH*SEQ

// ---------------- workspace layout (BYTE offsets), ~44.4 MB ----------------
#define OB_RELK  ((size_t)0)                      // bf16 [8][4095][64], col-swizzled
#define OB_QC    ((size_t)4194304)
#define OB_QP    ((size_t)8388608)
#define OB_K     ((size_t)12582912)
#define OB_V     ((size_t)16777216)               // V^T [bh][64][2048], chunk-swizzled
#define OB_OH    ((size_t)20971520)               // bf16 [4096][512]
// aliased (disjoint lifetimes):
#define OB_EMBH  OB_OH                            // dead after gemm_qr
#define OB_EMBL  ((size_t)(OB_OH + 1572864))
#define OB_XH    ((size_t)25165824)               // dead after gemm_qr
#define OB_XL    ((size_t)31457280)
#define OB_WQKVH ((size_t)37748736)               // dead after gemm_qr
#define OB_WQKVL ((size_t)40108032)
#define OB_WOH   ((size_t)42467328)               // out-proj weights
#define OB_WOL   ((size_t)43253760)
#define OB_WRH   ((size_t)44040192)
#define OB_WRL   ((size_t)44236800)

// RNE float -> bf16 bits (finite inputs only)
__device__ __forceinline__ unsigned f2bf(float f) {
  unsigned u = __float_as_uint(f);
  return (u + 0x7fffu + ((u >> 16) & 1u)) >> 16;
}
__device__ __forceinline__ void split2(float v, unsigned& hb, unsigned& lb) {
  hb = f2bf(v);
  const float back = __uint_as_float(hb << 16);
  lb = f2bf(v - back);
}

// async global->LDS 16B copy (m97 pattern; CK-style addrspace casts).
// l must be wave-uniform; HW writes l + lane*16. g is per-lane.
__device__ __forceinline__ void cp16(const short* g, short* l) {
  __builtin_amdgcn_global_load_lds(
      (__attribute__((address_space(1))) void*)(uintptr_t)(g),
      (__attribute__((address_space(3))) void*)(uint32_t)(uintptr_t)(l),
      16, 0, 0);
}

// ---------------- 1. fused prep: pos_emb + conv_split + 5 transposes ----------------
__global__ __launch_bounds__(256) void prep_all(
    const float* __restrict__ x,
    const float* __restrict__ Wq, const float* __restrict__ Wk,
    const float* __restrict__ Wv, const float* __restrict__ Wout,
    const float* __restrict__ Wrel,
    short* __restrict__ eh, short* __restrict__ el,
    short* __restrict__ xh, short* __restrict__ xl,
    short* __restrict__ wqkvh, short* __restrict__ wqkvl,
    short* __restrict__ woh, short* __restrict__ wol,
    short* __restrict__ wrh, short* __restrict__ wrl) {
  __shared__ float tile[32][33];
  const int blk = blockIdx.x;
  const int t = threadIdx.x;

  if (blk < 512) {
    const int row = blk * 8 + (t >> 5);
    const int j   = t & 31;
    if (row >= NPOS) {
      for (int c = j; c < 192; c += 32) { eh[(size_t)row * 192 + c] = 0; el[(size_t)row * 192 + c] = 0; }
      return;
    }
    const float dist = (float)(row - (SEQ - 1));
    const float ad   = fabsf(dist);
    const float hl    = exp2f(3.0f + 8.0f * (float)j / 31.0f);
    const float f_exp = exp2f(-ad / hl);
    const float width = exp2f((float)(j + 1)) - 1.0f;
    const float f_cm  = (width > ad) ? 1.0f : 0.0f;
    float prob;
    if (ad > 0.0f) {
      const float c   = 4.0f * (float)((j + 1) * (j + 1));
      const float r   = (float)(j + 1) / 16.0f;
      const float lu  = (c - 1.0f) * logf(ad) - r * ad;
      const float ln_ = lgammaf(c) - c * logf(r);
      prob = expf(lu - ln_) + 1e-8f;
    } else {
      prob = 1e-8f;
    }
    float mx = prob;
    for (int off = 16; off; off >>= 1) mx = fmaxf(mx, __shfl_xor(mx, off, 32));
    const float f_g = prob / mx;
    const float s = (dist > 0.f) ? 1.f : ((dist < 0.f) ? -1.f : 0.f);
    const float vals[6] = {f_exp, f_cm, f_g, s * f_exp, s * f_cm, s * f_g};
    short* ph = eh + (size_t)row * 192;
    short* pl = el + (size_t)row * 192;
#pragma unroll
    for (int q = 0; q < 6; q++) {
      unsigned hb, lb;
      split2(vals[q], hb, lb);
      ph[q * 32 + j] = (short)hb;
      pl[q * 32 + j] = (short)lb;
    }
    return;
  }

  if (blk < 3584) {
    const int i = (blk - 512) * 256 + t;
    const float4 v = ((const float4*)x)[i];
    unsigned h0, l0, h1, l1, h2, l2, h3, l3;
    split2(v.x, h0, l0); split2(v.y, h1, l1); split2(v.z, h2, l2); split2(v.w, h3, l3);
    *(uint2*)&xh[(size_t)i * 4] = make_uint2(h0 | (h1 << 16), h2 | (h3 << 16));
    *(uint2*)&xl[(size_t)i * 4] = make_uint2(l0 | (l1 << 16), l2 | (l3 << 16));
    return;
  }

  const float* src; short* dh; short* dl; int R, C, local;
  if (blk < 3968)      { local = blk - 3584; src = Wq;   dh = wqkvh;               dl = wqkvl;               R = DIMM; C = HD; }
  else if (blk < 4352) { local = blk - 3968; src = Wk;   dh = wqkvh + 512 * DIMM;  dl = wqkvl + 512 * DIMM;  R = DIMM; C = HD; }
  else if (blk < 4736) { local = blk - 4352; src = Wv;   dh = wqkvh + 1024 * DIMM; dl = wqkvl + 1024 * DIMM; R = DIMM; C = HD; }
  else if (blk < 5120) { local = blk - 4736; src = Wout; dh = woh;  dl = wol;  R = HD;  C = DIMM; }
  else                 { local = blk - 5120; src = Wrel; dh = wrh;  dl = wrl;  R = 192; C = HD; }
  const int ctiles = C / 32;
  const int c0 = (local % ctiles) * 32, r0 = (local / ctiles) * 32;
  {
    const int lr = t >> 3, lc = (t & 7) * 4;
    const float4 v = *(const float4*)&src[(size_t)(r0 + lr) * C + c0 + lc];
    tile[lr][lc] = v.x; tile[lr][lc + 1] = v.y; tile[lr][lc + 2] = v.z; tile[lr][lc + 3] = v.w;
  }
  __syncthreads();
  const int nn = t >> 3, kb = (t & 7) * 4;
  unsigned hb[4], lb[4];
#pragma unroll
  for (int e = 0; e < 4; e++) split2(tile[kb + e][nn], hb[e], lb[e]);
  const size_t o = (size_t)(c0 + nn) * R + r0 + kb;
  *(uint2*)&dh[o] = make_uint2(hb[0] | (hb[1] << 16), hb[2] | (hb[3] << 16));
  *(uint2*)&dl[o] = make_uint2(lb[0] | (lb[1] << 16), lb[2] | (lb[3] << 16));
}

// ---------------- 2. unified qkv+relk GEMM, dbuf cp16 + XCD swizzle ----------------
// R11: + XCD-contiguous block remap: each XCD's 64 consecutive-orig blocks span
// 2 full ntiles -> B-panels served from its own L2 instead of 8-way replication.
__global__ __launch_bounds__(256) void gemm_qr(
    const short* __restrict__ xh, const short* __restrict__ xl,
    const short* __restrict__ wqkvh, const short* __restrict__ wqkvl,
    const short* __restrict__ eh, const short* __restrict__ el,
    const short* __restrict__ wrh, const short* __restrict__ wrl,
    const float* __restrict__ cb, const float* __restrict__ pb,
    bf16* __restrict__ oq, bf16* __restrict__ oqp,
    bf16* __restrict__ ok, short* __restrict__ vtw,
    bf16* __restrict__ relk) {
  __shared__ short AsH[2][128][32];
  __shared__ short AsL[2][128][32];
  __shared__ short BsH[2][128][32];
  __shared__ short BsL[2][128][32];

  const int bxr = blockIdx.x;
  const int bx = (bxr & 7) * 64 + (bxr >> 3);   // bijective: 512 % 8 == 0
  const bool isq = bx < 384;
  const int lbx = isq ? bx : bx - 384;
  const int mt = lbx & 31, ntile = lbx >> 5;
  const int m0 = mt * 128, n0 = ntile * 128;
  const int KD = isq ? DIMM : 192;
  const short* Ah = isq ? xh : eh;
  const short* Al = isq ? xl : el;
  const short* Bh = isq ? wqkvh : wrh;
  const short* Bl = isq ? wqkvl : wrl;

  const int t = threadIdx.x, lane = t & 63, w = t >> 6;
  const int quad = lane >> 4, l15 = lane & 15;
  const int wm = (w >> 1) * 64, wn = (w & 1) * 64;

  const int srow = w * 32 + (lane >> 2);   // + c*16
  const int skof = (lane & 3) * 8;         // shorts within 64B row

  auto STAGE = [&](int bb, int k0) {
#pragma unroll
    for (int c = 0; c < 2; c++) {
      const size_t ra = (size_t)(m0 + srow + c * 16) * KD + k0 + skof;
      const size_t rb = (size_t)(n0 + srow + c * 16) * KD + k0 + skof;
      cp16(&Ah[ra], &AsH[bb][w * 32 + c * 16][0]);
      cp16(&Al[ra], &AsL[bb][w * 32 + c * 16][0]);
      cp16(&Bh[rb], &BsH[bb][w * 32 + c * 16][0]);
      cp16(&Bl[rb], &BsL[bb][w * 32 + c * 16][0]);
    }
  };

  f32x4 acc[4][4];
#pragma unroll
  for (int i = 0; i < 4; i++)
#pragma unroll
    for (int j = 0; j < 4; j++) acc[i][j] = (f32x4){0.f, 0.f, 0.f, 0.f};

  STAGE(0, 0);
  __syncthreads();   // tile 0 landed (vmcnt drain)

  int bb = 0;
  for (int k0 = 0; k0 < KD; k0 += 32) {
    if (k0 + 32 < KD) STAGE(bb ^ 1, k0 + 32);   // rides under this step's compute

    short8 amh[4], aml[4], bnh[4], bnl[4];
#pragma unroll
    for (int i = 0; i < 4; i++) {
      amh[i] = *(const short8*)&AsH[bb][wm + i * 16 + l15][quad * 8];
      aml[i] = *(const short8*)&AsL[bb][wm + i * 16 + l15][quad * 8];
      bnh[i] = *(const short8*)&BsH[bb][wn + i * 16 + l15][quad * 8];
      bnl[i] = *(const short8*)&BsL[bb][wn + i * 16 + l15][quad * 8];
    }
#pragma unroll
    for (int i = 0; i < 4; i++) {
#pragma unroll
      for (int j = 0; j < 4; j++) {
        acc[i][j] = __builtin_amdgcn_mfma_f32_16x16x32_bf16(amh[i], bnh[j], acc[i][j], 0, 0, 0);
        acc[i][j] = __builtin_amdgcn_mfma_f32_16x16x32_bf16(amh[i], bnl[j], acc[i][j], 0, 0, 0);
        acc[i][j] = __builtin_amdgcn_mfma_f32_16x16x32_bf16(aml[i], bnh[j], acc[i][j], 0, 0, 0);
      }
    }

    __syncthreads();   // drains prefetch (hidden under MFMAs); protects swap
    bb ^= 1;
  }

  if (isq) {
    const int sel = ntile >> 2;   // 0=q,1=k,2=v
    if (sel == 2) {
      // V^T write, swizzled: s' = s ^ ((d&7)<<3) within the 64-aligned chunk.
#pragma unroll
      for (int i = 0; i < 4; i++) {
#pragma unroll
        for (int j = 0; j < 4; j++) {
          const int n = n0 + wn + j * 16 + l15;
          const int hd_ = n & 511, hh = hd_ >> 6, d = hd_ & 63;
          const int m = m0 + wm + i * 16 + quad * 4;
          const int b = m >> 11, s = m & 2047;
          const int s_swz = s ^ ((d & 7) << 3);
          const uint2 pk = make_uint2(
              f2bf(acc[i][j][0]) | (f2bf(acc[i][j][1]) << 16),
              f2bf(acc[i][j][2]) | (f2bf(acc[i][j][3]) << 16));
          *(uint2*)&vtw[(((size_t)(b * HEADS + hh) * DK + d) * SEQ) + s_swz] = pk;
        }
      }
    } else {
#pragma unroll
      for (int i = 0; i < 4; i++) {
#pragma unroll
        for (int j = 0; j < 4; j++) {
          const int n = n0 + wn + j * 16 + l15;
          const int hd_ = n & 511, hh = hd_ >> 6, d = hd_ & 63;
#pragma unroll
          for (int g = 0; g < 4; g++) {
            const int m = m0 + wm + i * 16 + quad * 4 + g;
            const int b = m >> 11, s = m & 2047;
            const size_t idx = (((size_t)(b * HEADS + hh) * SEQ) + s) * DK + d;
            const float v = acc[i][j][g];
            if (sel == 0) {
              const float sv = v * 0.125f;   // dk^-0.5
              oq[idx]  = __float2bfloat16(sv + cb[hh * DK + d]);
              oqp[idx] = __float2bfloat16(sv + pb[hh * DK + d]);
            } else {
              ok[idx] = __float2bfloat16(v);
            }
          }
        }
      }
    }
  } else {
    // relk write, swizzled: d' = d ^ ((m&7)<<3)
#pragma unroll
    for (int i = 0; i < 4; i++) {
#pragma unroll
      for (int j = 0; j < 4; j++) {
        const int n = n0 + wn + j * 16 + l15;
        const int hh = n >> 6, d = n & 63;
#pragma unroll
        for (int g = 0; g < 4; g++) {
          const int m = m0 + wm + i * 16 + quad * 4 + g;
          if (m < NPOS)
            relk[((size_t)hh * NPOS + m) * DK + (d ^ ((m & 7) << 3))] =
                __float2bfloat16(acc[i][j][g]);
        }
      }
    }
  }
}

// ---------------- 3. out-projection GEMM, double-buffered cp16 staging ----------------
__global__ __launch_bounds__(256) void out_gemm(
    const short* __restrict__ Ahp,
    const short* __restrict__ Bhp, const short* __restrict__ Blp,
    const float* __restrict__ bias, float* __restrict__ ofp) {
  __shared__ short AsH[2][128][32];
  __shared__ short BsH[2][128][32];
  __shared__ short BsL[2][128][32];

  const int t = threadIdx.x, lane = t & 63, w = t >> 6;
  const int quad = lane >> 4, l15 = lane & 15;
  const int wm = (w >> 1) * 64, wn = (w & 1) * 64;
  const int m0 = blockIdx.x * 128, n0 = blockIdx.y * 128;
  const int srow = w * 32 + (lane >> 2);
  const int skof = (lane & 3) * 8;

  auto STAGE = [&](int bb, int k0) {
#pragma unroll
    for (int c = 0; c < 2; c++) {
      const size_t ra = (size_t)(m0 + srow + c * 16) * HD + k0 + skof;
      const size_t rb = (size_t)(n0 + srow + c * 16) * HD + k0 + skof;
      cp16(&Ahp[ra], &AsH[bb][w * 32 + c * 16][0]);
      cp16(&Bhp[rb], &BsH[bb][w * 32 + c * 16][0]);
      cp16(&Blp[rb], &BsL[bb][w * 32 + c * 16][0]);
    }
  };

  f32x4 acc[4][4];
#pragma unroll
  for (int i = 0; i < 4; i++)
#pragma unroll
    for (int j = 0; j < 4; j++) acc[i][j] = (f32x4){0.f, 0.f, 0.f, 0.f};

  STAGE(0, 0);
  __syncthreads();

  int bb = 0;
  for (int k0 = 0; k0 < HD; k0 += 32) {
    if (k0 + 32 < HD) STAGE(bb ^ 1, k0 + 32);

    short8 amh[4], bnh[4], bnl[4];
#pragma unroll
    for (int i = 0; i < 4; i++) {
      amh[i] = *(const short8*)&AsH[bb][wm + i * 16 + l15][quad * 8];
      bnh[i] = *(const short8*)&BsH[bb][wn + i * 16 + l15][quad * 8];
      bnl[i] = *(const short8*)&BsL[bb][wn + i * 16 + l15][quad * 8];
    }
#pragma unroll
    for (int i = 0; i < 4; i++) {
#pragma unroll
      for (int j = 0; j < 4; j++) {
        acc[i][j] = __builtin_amdgcn_mfma_f32_16x16x32_bf16(amh[i], bnh[j], acc[i][j], 0, 0, 0);
        acc[i][j] = __builtin_amdgcn_mfma_f32_16x16x32_bf16(amh[i], bnl[j], acc[i][j], 0, 0, 0);
      }
    }

    __syncthreads();
    bb ^= 1;
  }

#pragma unroll
  for (int i = 0; i < 4; i++) {
#pragma unroll
    for (int j = 0; j < 4; j++) {
      const int n = n0 + wn + j * 16 + l15;
      const float bv = bias[n];
#pragma unroll
      for (int g = 0; g < 4; g++) {
        const int m = m0 + wm + i * 16 + quad * 4 + g;
        ofp[(size_t)m * DIMM + n] = acc[i][j][g] + bv;
      }
    }
  }
}

// ---------------- 4. attention: 8-wave, both j-halves per block, in-kernel merge ----------------
// R11: waves 0-3 = j in [0,1024), waves 4-7 = j in [1024,2048) (identical R9
// per-half structure, lockstep barriers). Epilogue: half-1 parks O/l partials in
// the dead V buffer; half-0 normalizes and writes oh bf16 directly. Deletes the
// merge kernel + ~50MB Op/Lp HBM round-trip. V single-buffered per half, staged
// AFTER barrier A (cover = next tile's QK^T+softmax; drained at next C before PV).
// LDS = ring 2x16K + V 2x8K + Pw 8x2K = 65536 -> capacity 2, 16 waves/CU.
__global__ __launch_bounds__(512) void attn_mfma4(
    const short* __restrict__ qc, const short* __restrict__ qp,
    const short* __restrict__ kg, const short* __restrict__ vt,
    const short* __restrict__ relk,
    short* __restrict__ oh) {
  __shared__ __align__(16) short RelR[2][128 * 64];  // per-half 2-chunk rel ring
  __shared__ __align__(16) short VtS[2][64 * 64];    // per-half V^T tile (single)
  __shared__ __align__(16) short Pw[8][16][64];      // per-wave P, XOR-swizzled

  const int bid = blockIdx.x;
  const int swz = (bid & 7) * 64 + (bid >> 3);    // bijective: 512 % 8 == 0
  const int i0  = (swz & 31) * 64;
  const int bh  = swz >> 5;
  const int h   = bh & 7;

  const int t    = threadIdx.x;
  const int lane = t & 63;
  const int w    = t >> 6;          // 0..7
  const int wl   = w & 3;           // i-sub-wave within half
  const int half = w >> 2;          // j-half
  const int jb   = half * (SEQ / 2);
  const int quad = lane >> 4;
  const int l15  = lane & 15;
  const int x    = (l15 & 7) << 3;  // swizzle key (shorts)

  short8 qcA[2], qpA[2];
  {
    const size_t qrow = ((size_t)bh * SEQ + i0 + wl * 16 + l15) * DK + quad * 8;
    qcA[0] = *(const short8*)(qc + qrow);
    qcA[1] = *(const short8*)(qc + qrow + 32);
    qpA[0] = *(const short8*)(qp + qrow);
    qpA[1] = *(const short8*)(qp + qrow + 32);
  }

  int idxg[4]; bool selg[4];
#pragma unroll
  for (int g = 0; g < 4; g++) {
    const int r = quad * 4 + g;
    idxg[g] = (((lane & 48) | ((l15 + 15 - r) & 15)) << 2);
    selg[g] = (l15 <= r);
  }

  short8 ones8;
#pragma unroll
  for (int e = 0; e < 8; e++) ones8[e] = (short)0x3F80;   // bf16 1.0

  f32x4 oacc[4];
#pragma unroll
  for (int dt = 0; dt < 4; dt++) oacc[dt] = (f32x4){0.f, 0.f, 0.f, 0.f};
  f32x4 lacc = (f32x4){0.f, 0.f, 0.f, 0.f};

  const short* kbase = kg + (size_t)bh * SEQ * DK;
  const short* vbase = vt + (size_t)bh * DK * SEQ;
  // rel rows indexed as (j - i0 + 1984) + offset; fold head base + (1984 - i0).
  const short* rbase = relk + ((size_t)(h * NPOS + 1984 - i0)) * DK;

  const int rb_w = 48 - 16 * wl;

  // stage this half's V^T tile at j0n: 8 cp16 per half, 2 per wave (conflict-free)
  auto STAGEV = [&](int j0n) {
#pragma unroll
    for (int cc = 0; cc < 2; cc++) {
      const int c = wl * 2 + cc;
      cp16(vbase + (size_t)(c * 8 + (lane >> 3)) * SEQ + j0n + (lane & 7) * 8,
           &VtS[half][c * 512]);
    }
  };

  // ---- prologue ----
  // rel slots 16..127 = rows jb+16..jb+127 (14 cp16 per half, wave-split)
#pragma unroll
  for (int cc = 0; cc < 4; cc++) {
    const int c = wl + cc * 4;
    if (c < 14)
      cp16(rbase + (size_t)(jb + 16) * DK + c * 512 + lane * 8,
           &RelR[half][1024 + c * 512]);
  }
  STAGEV(jb);
  // carry init: bpermuted rel window 0 of tile 0 (direct global, swizzled cols)
  f32x4 bpp_carry;
  {
    const short* rl = rbase + (size_t)(jb + rb_w + l15) * DK;
    short8 b0 = *(const short8*)(rl + ((quad * 8) ^ x));
    short8 b1 = *(const short8*)(rl + ((quad * 8 + 32) ^ x));
    f32x4 a = (f32x4){0.f, 0.f, 0.f, 0.f};
    a = __builtin_amdgcn_mfma_f32_16x16x32_bf16(qpA[0], b0, a, 0, 0, 0);
    a = __builtin_amdgcn_mfma_f32_16x16x32_bf16(qpA[1], b1, a, 0, 0, 0);
#pragma unroll
    for (int g = 0; g < 4; g++)
      bpp_carry[g] = __int_as_float(__builtin_amdgcn_ds_bpermute(idxg[g], __float_as_int(a[g])));
  }
  __syncthreads();   // (A0) prologue staging landed

  for (int jt = 0; jt < 16; jt++) {
    const int j0 = jb + jt * 64;
    const int rowoff = (jt & 1) * 64;   // ring chunk parity for this tile's base

    // QK^T: K fragments direct from global (independent batch, latency-tolerant)
    f32x4 sacc[4];
#pragma unroll
    for (int nt = 0; nt < 4; nt++) {
      const short* kr = kbase + (size_t)(j0 + nt * 16 + l15) * DK + quad * 8;
      short8 b0 = *(const short8*)kr;
      short8 b1 = *(const short8*)(kr + 32);
      f32x4 a = (f32x4){0.f, 0.f, 0.f, 0.f};
      a = __builtin_amdgcn_mfma_f32_16x16x32_bf16(qcA[0], b0, a, 0, 0, 0);
      a = __builtin_amdgcn_mfma_f32_16x16x32_bf16(qcA[1], b1, a, 0, 0, 0);
      sacc[nt] = a;
    }

    f32x4 bpp = bpp_carry;

#pragma unroll
    for (int nt = 0; nt < 4; nt++) {
      f32x4 rcur;
      {
        // ring slot for global row j0+16+rb_w+nt*16+l15 (jb ≡ 0 mod 128)
        const int slot = (rowoff + 16 + rb_w + nt * 16 + l15) & 127;
        const short* rl = &RelR[half][slot * 64];
        short8 b0 = *(const short8*)(rl + ((quad * 8) ^ x));
        short8 b1 = *(const short8*)(rl + ((quad * 8 + 32) ^ x));
        f32x4 a = (f32x4){0.f, 0.f, 0.f, 0.f};
        a = __builtin_amdgcn_mfma_f32_16x16x32_bf16(qpA[0], b0, a, 0, 0, 0);
        a = __builtin_amdgcn_mfma_f32_16x16x32_bf16(qpA[1], b1, a, 0, 0, 0);
        rcur = a;
      }
      f32x4 bpc;
#pragma unroll
      for (int g = 0; g < 4; g++)
        bpc[g] = __int_as_float(__builtin_amdgcn_ds_bpermute(idxg[g], __float_as_int(rcur[g])));
#pragma unroll
      for (int g = 0; g < 4; g++) {
        const float relv = selg[g] ? bpp[g] : bpc[g];
        const float s = sacc[nt][g] + relv;
        const float p = __expf(s - 12.0f);
        const int prow = quad * 4 + g;
        Pw[w][prow][(nt * 16 + l15) ^ ((prow & 7) << 3)] = (short)f2bf(p);
      }
      bpp = bpc;
    }
    bpp_carry = bpp;   // window 4 of this tile == window 0 of the next

    __syncthreads();   // (C) ring reads done; drains V prefetch issued last iter

    // rel prefetch for tile jt+1: rows [j0+128, j0+192) -> slots [rowoff, rowoff+64)
    if (jt < 15) {
      const short* rsrc = rbase + (size_t)(j0 + 128) * DK;
#pragma unroll
      for (int cc = 0; cc < 2; cc++) {
        const int c = wl * 2 + cc;
        cp16(rsrc + c * 512 + lane * 8, &RelR[half][rowoff * 64 + c * 512]);
      }
    }

    // PV: hides the ring prefetch; VtS[half] staged last iter (drained at C)
#pragma unroll
    for (int ks = 0; ks < 2; ks++) {
      short8 pA = *(const short8*)&Pw[w][l15][(ks * 32 + quad * 8) ^ x];
      lacc = __builtin_amdgcn_mfma_f32_16x16x32_bf16(pA, ones8, lacc, 0, 0, 0);
#pragma unroll
      for (int dt = 0; dt < 4; dt++) {
        const short* vl = &VtS[half][(dt * 16 + l15) * 64 + ((ks * 32 + quad * 8) ^ x)];
        short8 vB = *(const short8*)vl;
        oacc[dt] = __builtin_amdgcn_mfma_f32_16x16x32_bf16(pA, vB, oacc[dt], 0, 0, 0);
      }
    }

    __syncthreads();   // (A) PV reads done -> safe to overwrite VtS; ring pref drained
    if (jt < 15) STAGEV(j0 + 64);   // lands by next tile's (C)
  }

  // ---- in-block merge: half 1 parks partials, half 0 combines + writes oh ----
  float* oscr = (float*)&VtS[0][0];   // [4 pairs][16 rows][64 d] f32 = 16 KB
  float* lscr = (float*)&RelR[0][0];  // [4 pairs][16 rows] f32
  if (w >= 4) {
#pragma unroll
    for (int g = 0; g < 4; g++) {
      const int r = quad * 4 + g;
#pragma unroll
      for (int dt = 0; dt < 4; dt++)
        oscr[(wl * 16 + r) * 64 + dt * 16 + l15] = oacc[dt][g];
      if (l15 == 0) lscr[wl * 16 + r] = lacc[g];
    }
  }
  __syncthreads();
  if (w < 4) {
    const int b = bh >> 3, hh = bh & 7;
#pragma unroll
    for (int g = 0; g < 4; g++) {
      const int r = quad * 4 + g;
      const float linv = 1.0f / (lacc[g] + lscr[wl * 16 + r]);
      const size_t mrow = (size_t)(b * SEQ + i0 + wl * 16 + r) * HD + hh * 64;
#pragma unroll
      for (int dt = 0; dt < 4; dt++) {
        const float o = oacc[dt][g] + oscr[(wl * 16 + r) * 64 + dt * 16 + l15];
        oh[mrow + dt * 16 + l15] = (short)f2bf(o * linv);
      }
    }
  }
}

// ---------------- launch ----------------
extern "C" void kernel_launch(void* const* d_in, const int* in_sizes, int n_in,
                              void* d_out, int out_size, void* d_ws, size_t ws_size,
                              hipStream_t stream) {
  (void)in_sizes; (void)n_in; (void)out_size; (void)ws_size;
  const float* x    = (const float*)d_in[0];
  const float* Wq   = (const float*)d_in[1];
  const float* Wk   = (const float*)d_in[2];
  const float* Wv   = (const float*)d_in[3];
  const float* Wrel = (const float*)d_in[4];
  const float* Wout = (const float*)d_in[5];
  const float* bout = (const float*)d_in[6];
  const float* cb   = (const float*)d_in[7];
  const float* pb   = (const float*)d_in[8];
  float* out = (float*)d_out;

  char* ws = (char*)d_ws;
  bf16*  relk = (bf16*)(ws + OB_RELK);
  bf16*  qc   = (bf16*)(ws + OB_QC);
  bf16*  qp   = (bf16*)(ws + OB_QP);
  bf16*  kk   = (bf16*)(ws + OB_K);
  short* vt   = (short*)(ws + OB_V);    // V^T written directly by gemm_qr (swizzled)
  short* oh   = (short*)(ws + OB_OH);   // written directly by attn (merged)
  short* embh = (short*)(ws + OB_EMBH);
  short* embl = (short*)(ws + OB_EMBL);
  short* xh   = (short*)(ws + OB_XH);
  short* xl   = (short*)(ws + OB_XL);
  short* wqh  = (short*)(ws + OB_WQKVH);
  short* wql  = (short*)(ws + OB_WQKVL);
  short* woh  = (short*)(ws + OB_WOH);
  short* wol  = (short*)(ws + OB_WOL);
  short* wrh  = (short*)(ws + OB_WRH);
  short* wrl  = (short*)(ws + OB_WRL);

  hipLaunchKernelGGL(prep_all, dim3(5216), dim3(256), 0, stream,
                     x, Wq, Wk, Wv, Wout, Wrel,
                     embh, embl, xh, xl, wqh, wql, woh, wol, wrh, wrl);
  hipLaunchKernelGGL(gemm_qr, dim3(512), dim3(256), 0, stream,
                     xh, xl, wqh, wql, embh, embl, wrh, wrl,
                     cb, pb, qc, qp, kk, vt, relk);
  hipLaunchKernelGGL(attn_mfma4, dim3(512), dim3(512), 0, stream,
                     (const short*)qc, (const short*)qp, (const short*)kk,
                     (const short*)vt, (const short*)relk, oh);
  hipLaunchKernelGGL(out_gemm, dim3(32, 6), dim3(256), 0, stream,
                     (const short*)oh, woh, wol, bout, out);
}

// Round 12
// 204.583 us; speedup vs baseline: 1.3623x; 1.0505x over previous
//
#include <hip/hip_runtime.h>
#include <hip/hip_bf16.h>
#include <math.h>
#include <stdint.h>

typedef __hip_bfloat16 bf16;
typedef __attribute__((ext_vector_type(8))) short short8;  // 8 bf16 = 4 VGPRs
typedef __attribute__((ext_vector_type(4))) float f32x4;

#define SEQ   2048
#define NPOS  4095          // 2*SEQ-1
#define DIMM  768
#define HEADS 8
#define DK    64
#define HD    512           // HEADS*DK
#define BATCH 2
#define BH    16            // BATCH*HEADS
#define ROWS  4096          // BATCH*SEQ

// ---------------- workspace layout (BYTE offsets), ~44.4 MB ----------------
#define OB_RELK  ((size_t)0)                      // bf16 [8][4095][64], col-swizzled
#define OB_QC    ((size_t)4194304)
#define OB_QP    ((size_t)8388608)
#define OB_K     ((size_t)12582912)
#define OB_V     ((size_t)16777216)               // V^T [bh][64][2048], chunk-swizzled
#define OB_OH    ((size_t)20971520)               // bf16 [4096][512]
// aliased (disjoint lifetimes):
#define OB_EMBH  OB_OH                            // dead after gemm_qr
#define OB_EMBL  ((size_t)(OB_OH + 1572864))
#define OB_XH    ((size_t)25165824)               // dead after gemm_qr
#define OB_XL    ((size_t)31457280)
#define OB_WQKVH ((size_t)37748736)               // dead after gemm_qr
#define OB_WQKVL ((size_t)40108032)
#define OB_WOH   ((size_t)42467328)               // out-proj weights
#define OB_WOL   ((size_t)43253760)
#define OB_WRH   ((size_t)44040192)
#define OB_WRL   ((size_t)44236800)

// RNE float -> bf16 bits (finite inputs only)
__device__ __forceinline__ unsigned f2bf(float f) {
  unsigned u = __float_as_uint(f);
  return (u + 0x7fffu + ((u >> 16) & 1u)) >> 16;
}
__device__ __forceinline__ void split2(float v, unsigned& hb, unsigned& lb) {
  hb = f2bf(v);
  const float back = __uint_as_float(hb << 16);
  lb = f2bf(v - back);
}

// async global->LDS 16B copy (m97 pattern; CK-style addrspace casts).
// l must be wave-uniform; HW writes l + lane*16. g is per-lane.
__device__ __forceinline__ void cp16(const short* g, short* l) {
  __builtin_amdgcn_global_load_lds(
      (__attribute__((address_space(1))) void*)(uintptr_t)(g),
      (__attribute__((address_space(3))) void*)(uint32_t)(uintptr_t)(l),
      16, 0, 0);
}

// ---------------- 1. fused prep: pos_emb + conv_split + 5 transposes ----------------
__global__ __launch_bounds__(256) void prep_all(
    const float* __restrict__ x,
    const float* __restrict__ Wq, const float* __restrict__ Wk,
    const float* __restrict__ Wv, const float* __restrict__ Wout,
    const float* __restrict__ Wrel,
    short* __restrict__ eh, short* __restrict__ el,
    short* __restrict__ xh, short* __restrict__ xl,
    short* __restrict__ wqkvh, short* __restrict__ wqkvl,
    short* __restrict__ woh, short* __restrict__ wol,
    short* __restrict__ wrh, short* __restrict__ wrl) {
  __shared__ float tile[32][33];
  const int blk = blockIdx.x;
  const int t = threadIdx.x;

  if (blk < 512) {
    const int row = blk * 8 + (t >> 5);
    const int j   = t & 31;
    if (row >= NPOS) {
      for (int c = j; c < 192; c += 32) { eh[(size_t)row * 192 + c] = 0; el[(size_t)row * 192 + c] = 0; }
      return;
    }
    const float dist = (float)(row - (SEQ - 1));
    const float ad   = fabsf(dist);
    const float hl    = exp2f(3.0f + 8.0f * (float)j / 31.0f);
    const float f_exp = exp2f(-ad / hl);
    const float width = exp2f((float)(j + 1)) - 1.0f;
    const float f_cm  = (width > ad) ? 1.0f : 0.0f;
    float prob;
    if (ad > 0.0f) {
      const float c   = 4.0f * (float)((j + 1) * (j + 1));
      const float r   = (float)(j + 1) / 16.0f;
      const float lu  = (c - 1.0f) * logf(ad) - r * ad;
      const float ln_ = lgammaf(c) - c * logf(r);
      prob = expf(lu - ln_) + 1e-8f;
    } else {
      prob = 1e-8f;
    }
    float mx = prob;
    for (int off = 16; off; off >>= 1) mx = fmaxf(mx, __shfl_xor(mx, off, 32));
    const float f_g = prob / mx;
    const float s = (dist > 0.f) ? 1.f : ((dist < 0.f) ? -1.f : 0.f);
    const float vals[6] = {f_exp, f_cm, f_g, s * f_exp, s * f_cm, s * f_g};
    short* ph = eh + (size_t)row * 192;
    short* pl = el + (size_t)row * 192;
#pragma unroll
    for (int q = 0; q < 6; q++) {
      unsigned hb, lb;
      split2(vals[q], hb, lb);
      ph[q * 32 + j] = (short)hb;
      pl[q * 32 + j] = (short)lb;
    }
    return;
  }

  if (blk < 3584) {
    const int i = (blk - 512) * 256 + t;
    const float4 v = ((const float4*)x)[i];
    unsigned h0, l0, h1, l1, h2, l2, h3, l3;
    split2(v.x, h0, l0); split2(v.y, h1, l1); split2(v.z, h2, l2); split2(v.w, h3, l3);
    *(uint2*)&xh[(size_t)i * 4] = make_uint2(h0 | (h1 << 16), h2 | (h3 << 16));
    *(uint2*)&xl[(size_t)i * 4] = make_uint2(l0 | (l1 << 16), l2 | (l3 << 16));
    return;
  }

  const float* src; short* dh; short* dl; int R, C, local;
  if (blk < 3968)      { local = blk - 3584; src = Wq;   dh = wqkvh;               dl = wqkvl;               R = DIMM; C = HD; }
  else if (blk < 4352) { local = blk - 3968; src = Wk;   dh = wqkvh + 512 * DIMM;  dl = wqkvl + 512 * DIMM;  R = DIMM; C = HD; }
  else if (blk < 4736) { local = blk - 4352; src = Wv;   dh = wqkvh + 1024 * DIMM; dl = wqkvl + 1024 * DIMM; R = DIMM; C = HD; }
  else if (blk < 5120) { local = blk - 4736; src = Wout; dh = woh;  dl = wol;  R = HD;  C = DIMM; }
  else                 { local = blk - 5120; src = Wrel; dh = wrh;  dl = wrl;  R = 192; C = HD; }
  const int ctiles = C / 32;
  const int c0 = (local % ctiles) * 32, r0 = (local / ctiles) * 32;
  {
    const int lr = t >> 3, lc = (t & 7) * 4;
    const float4 v = *(const float4*)&src[(size_t)(r0 + lr) * C + c0 + lc];
    tile[lr][lc] = v.x; tile[lr][lc + 1] = v.y; tile[lr][lc + 2] = v.z; tile[lr][lc + 3] = v.w;
  }
  __syncthreads();
  const int nn = t >> 3, kb = (t & 7) * 4;
  unsigned hb[4], lb[4];
#pragma unroll
  for (int e = 0; e < 4; e++) split2(tile[kb + e][nn], hb[e], lb[e]);
  const size_t o = (size_t)(c0 + nn) * R + r0 + kb;
  *(uint2*)&dh[o] = make_uint2(hb[0] | (hb[1] << 16), hb[2] | (hb[3] << 16));
  *(uint2*)&dl[o] = make_uint2(lb[0] | (lb[1] << 16), lb[2] | (lb[3] << 16));
}

// ---------------- 2. unified qkv+relk GEMM, dbuf cp16 (swizzle REVERTED per R11 ledger) ----------------
// R11 ledger: attn -1.2, merge -8 deleted, total -0.2 => XCD remap here cost ~+9us.
// Mechanism: A (12.6MB xh+xl) is the dominant shared operand; the remap spread all
// 32 mtiles across each XCD, hurting A-locality to save tiny B-panels. Reverted.
__global__ __launch_bounds__(256) void gemm_qr(
    const short* __restrict__ xh, const short* __restrict__ xl,
    const short* __restrict__ wqkvh, const short* __restrict__ wqkvl,
    const short* __restrict__ eh, const short* __restrict__ el,
    const short* __restrict__ wrh, const short* __restrict__ wrl,
    const float* __restrict__ cb, const float* __restrict__ pb,
    bf16* __restrict__ oq, bf16* __restrict__ oqp,
    bf16* __restrict__ ok, short* __restrict__ vtw,
    bf16* __restrict__ relk) {
  __shared__ short AsH[2][128][32];
  __shared__ short AsL[2][128][32];
  __shared__ short BsH[2][128][32];
  __shared__ short BsL[2][128][32];

  const int bx = blockIdx.x;
  const bool isq = bx < 384;
  const int lbx = isq ? bx : bx - 384;
  const int mt = lbx & 31, ntile = lbx >> 5;
  const int m0 = mt * 128, n0 = ntile * 128;
  const int KD = isq ? DIMM : 192;
  const short* Ah = isq ? xh : eh;
  const short* Al = isq ? xl : el;
  const short* Bh = isq ? wqkvh : wrh;
  const short* Bl = isq ? wqkvl : wrl;

  const int t = threadIdx.x, lane = t & 63, w = t >> 6;
  const int quad = lane >> 4, l15 = lane & 15;
  const int wm = (w >> 1) * 64, wn = (w & 1) * 64;

  const int srow = w * 32 + (lane >> 2);   // + c*16
  const int skof = (lane & 3) * 8;         // shorts within 64B row

  auto STAGE = [&](int bb, int k0) {
#pragma unroll
    for (int c = 0; c < 2; c++) {
      const size_t ra = (size_t)(m0 + srow + c * 16) * KD + k0 + skof;
      const size_t rb = (size_t)(n0 + srow + c * 16) * KD + k0 + skof;
      cp16(&Ah[ra], &AsH[bb][w * 32 + c * 16][0]);
      cp16(&Al[ra], &AsL[bb][w * 32 + c * 16][0]);
      cp16(&Bh[rb], &BsH[bb][w * 32 + c * 16][0]);
      cp16(&Bl[rb], &BsL[bb][w * 32 + c * 16][0]);
    }
  };

  f32x4 acc[4][4];
#pragma unroll
  for (int i = 0; i < 4; i++)
#pragma unroll
    for (int j = 0; j < 4; j++) acc[i][j] = (f32x4){0.f, 0.f, 0.f, 0.f};

  STAGE(0, 0);
  __syncthreads();   // tile 0 landed (vmcnt drain)

  int bb = 0;
  for (int k0 = 0; k0 < KD; k0 += 32) {
    if (k0 + 32 < KD) STAGE(bb ^ 1, k0 + 32);   // rides under this step's compute

    short8 amh[4], aml[4], bnh[4], bnl[4];
#pragma unroll
    for (int i = 0; i < 4; i++) {
      amh[i] = *(const short8*)&AsH[bb][wm + i * 16 + l15][quad * 8];
      aml[i] = *(const short8*)&AsL[bb][wm + i * 16 + l15][quad * 8];
      bnh[i] = *(const short8*)&BsH[bb][wn + i * 16 + l15][quad * 8];
      bnl[i] = *(const short8*)&BsL[bb][wn + i * 16 + l15][quad * 8];
    }
#pragma unroll
    for (int i = 0; i < 4; i++) {
#pragma unroll
      for (int j = 0; j < 4; j++) {
        acc[i][j] = __builtin_amdgcn_mfma_f32_16x16x32_bf16(amh[i], bnh[j], acc[i][j], 0, 0, 0);
        acc[i][j] = __builtin_amdgcn_mfma_f32_16x16x32_bf16(amh[i], bnl[j], acc[i][j], 0, 0, 0);
        acc[i][j] = __builtin_amdgcn_mfma_f32_16x16x32_bf16(aml[i], bnh[j], acc[i][j], 0, 0, 0);
      }
    }

    __syncthreads();   // drains prefetch (hidden under MFMAs); protects swap
    bb ^= 1;
  }

  if (isq) {
    const int sel = ntile >> 2;   // 0=q,1=k,2=v
    if (sel == 2) {
      // V^T write, swizzled: s' = s ^ ((d&7)<<3) within the 64-aligned chunk.
#pragma unroll
      for (int i = 0; i < 4; i++) {
#pragma unroll
        for (int j = 0; j < 4; j++) {
          const int n = n0 + wn + j * 16 + l15;
          const int hd_ = n & 511, hh = hd_ >> 6, d = hd_ & 63;
          const int m = m0 + wm + i * 16 + quad * 4;
          const int b = m >> 11, s = m & 2047;
          const int s_swz = s ^ ((d & 7) << 3);
          const uint2 pk = make_uint2(
              f2bf(acc[i][j][0]) | (f2bf(acc[i][j][1]) << 16),
              f2bf(acc[i][j][2]) | (f2bf(acc[i][j][3]) << 16));
          *(uint2*)&vtw[(((size_t)(b * HEADS + hh) * DK + d) * SEQ) + s_swz] = pk;
        }
      }
    } else {
#pragma unroll
      for (int i = 0; i < 4; i++) {
#pragma unroll
        for (int j = 0; j < 4; j++) {
          const int n = n0 + wn + j * 16 + l15;
          const int hd_ = n & 511, hh = hd_ >> 6, d = hd_ & 63;
#pragma unroll
          for (int g = 0; g < 4; g++) {
            const int m = m0 + wm + i * 16 + quad * 4 + g;
            const int b = m >> 11, s = m & 2047;
            const size_t idx = (((size_t)(b * HEADS + hh) * SEQ) + s) * DK + d;
            const float v = acc[i][j][g];
            if (sel == 0) {
              const float sv = v * 0.125f;   // dk^-0.5
              oq[idx]  = __float2bfloat16(sv + cb[hh * DK + d]);
              oqp[idx] = __float2bfloat16(sv + pb[hh * DK + d]);
            } else {
              ok[idx] = __float2bfloat16(v);
            }
          }
        }
      }
    }
  } else {
    // relk write, swizzled: d' = d ^ ((m&7)<<3)
#pragma unroll
    for (int i = 0; i < 4; i++) {
#pragma unroll
      for (int j = 0; j < 4; j++) {
        const int n = n0 + wn + j * 16 + l15;
        const int hh = n >> 6, d = n & 63;
#pragma unroll
        for (int g = 0; g < 4; g++) {
          const int m = m0 + wm + i * 16 + quad * 4 + g;
          if (m < NPOS)
            relk[((size_t)hh * NPOS + m) * DK + (d ^ ((m & 7) << 3))] =
                __float2bfloat16(acc[i][j][g]);
        }
      }
    }
  }
}

// ---------------- 3. out-projection GEMM, 64x64 tiles (R12 retile) ----------------
// Old: 128x128, grid 32x6=192 blocks -> 768 waves on 1024 SIMDs (<1 wave/SIMD,
// no latency hiding). New: 64x64 tiles, grid 64x12=768 blocks, LDS 24576
// (capacity 6) -> 3 blk/CU, 12 waves/CU. Same dbuf cp16 pipeline.
__global__ __launch_bounds__(256) void out_gemm(
    const short* __restrict__ Ahp,
    const short* __restrict__ Bhp, const short* __restrict__ Blp,
    const float* __restrict__ bias, float* __restrict__ ofp) {
  __shared__ short AsH[2][64][32];
  __shared__ short BsH[2][64][32];
  __shared__ short BsL[2][64][32];

  const int t = threadIdx.x, lane = t & 63, w = t >> 6;
  const int quad = lane >> 4, l15 = lane & 15;
  const int wm = (w >> 1) * 32, wn = (w & 1) * 32;
  const int m0 = blockIdx.x * 64, n0 = blockIdx.y * 64;
  const int srow = w * 16 + (lane >> 2);   // staging row (wave w covers 16 rows)
  const int skof = (lane & 3) * 8;

  auto STAGE = [&](int bb, int k0) {
    const size_t ra = (size_t)(m0 + srow) * HD + k0 + skof;
    const size_t rb = (size_t)(n0 + srow) * HD + k0 + skof;
    cp16(&Ahp[ra], &AsH[bb][w * 16][0]);
    cp16(&Bhp[rb], &BsH[bb][w * 16][0]);
    cp16(&Blp[rb], &BsL[bb][w * 16][0]);
  };

  f32x4 acc[2][2];
#pragma unroll
  for (int i = 0; i < 2; i++)
#pragma unroll
    for (int j = 0; j < 2; j++) acc[i][j] = (f32x4){0.f, 0.f, 0.f, 0.f};

  STAGE(0, 0);
  __syncthreads();

  int bb = 0;
  for (int k0 = 0; k0 < HD; k0 += 32) {
    if (k0 + 32 < HD) STAGE(bb ^ 1, k0 + 32);

    short8 amh[2], bnh[2], bnl[2];
#pragma unroll
    for (int i = 0; i < 2; i++) {
      amh[i] = *(const short8*)&AsH[bb][wm + i * 16 + l15][quad * 8];
      bnh[i] = *(const short8*)&BsH[bb][wn + i * 16 + l15][quad * 8];
      bnl[i] = *(const short8*)&BsL[bb][wn + i * 16 + l15][quad * 8];
    }
#pragma unroll
    for (int i = 0; i < 2; i++) {
#pragma unroll
      for (int j = 0; j < 2; j++) {
        acc[i][j] = __builtin_amdgcn_mfma_f32_16x16x32_bf16(amh[i], bnh[j], acc[i][j], 0, 0, 0);
        acc[i][j] = __builtin_amdgcn_mfma_f32_16x16x32_bf16(amh[i], bnl[j], acc[i][j], 0, 0, 0);
      }
    }

    __syncthreads();
    bb ^= 1;
  }

#pragma unroll
  for (int i = 0; i < 2; i++) {
#pragma unroll
    for (int j = 0; j < 2; j++) {
      const int n = n0 + wn + j * 16 + l15;
      const float bv = bias[n];
#pragma unroll
      for (int g = 0; g < 4; g++) {
        const int m = m0 + wm + i * 16 + quad * 4 + g;
        ofp[(size_t)m * DIMM + n] = acc[i][j][g] + bv;
      }
    }
  }
}

// ---------------- 4. attention: 8-wave, both j-halves per block, in-kernel merge (R11, unchanged) ----------------
__global__ __launch_bounds__(512) void attn_mfma4(
    const short* __restrict__ qc, const short* __restrict__ qp,
    const short* __restrict__ kg, const short* __restrict__ vt,
    const short* __restrict__ relk,
    short* __restrict__ oh) {
  __shared__ __align__(16) short RelR[2][128 * 64];  // per-half 2-chunk rel ring
  __shared__ __align__(16) short VtS[2][64 * 64];    // per-half V^T tile (single)
  __shared__ __align__(16) short Pw[8][16][64];      // per-wave P, XOR-swizzled

  const int bid = blockIdx.x;
  const int swz = (bid & 7) * 64 + (bid >> 3);    // bijective: 512 % 8 == 0
  const int i0  = (swz & 31) * 64;
  const int bh  = swz >> 5;
  const int h   = bh & 7;

  const int t    = threadIdx.x;
  const int lane = t & 63;
  const int w    = t >> 6;          // 0..7
  const int wl   = w & 3;           // i-sub-wave within half
  const int half = w >> 2;          // j-half
  const int jb   = half * (SEQ / 2);
  const int quad = lane >> 4;
  const int l15  = lane & 15;
  const int x    = (l15 & 7) << 3;  // swizzle key (shorts)

  short8 qcA[2], qpA[2];
  {
    const size_t qrow = ((size_t)bh * SEQ + i0 + wl * 16 + l15) * DK + quad * 8;
    qcA[0] = *(const short8*)(qc + qrow);
    qcA[1] = *(const short8*)(qc + qrow + 32);
    qpA[0] = *(const short8*)(qp + qrow);
    qpA[1] = *(const short8*)(qp + qrow + 32);
  }

  int idxg[4]; bool selg[4];
#pragma unroll
  for (int g = 0; g < 4; g++) {
    const int r = quad * 4 + g;
    idxg[g] = (((lane & 48) | ((l15 + 15 - r) & 15)) << 2);
    selg[g] = (l15 <= r);
  }

  short8 ones8;
#pragma unroll
  for (int e = 0; e < 8; e++) ones8[e] = (short)0x3F80;   // bf16 1.0

  f32x4 oacc[4];
#pragma unroll
  for (int dt = 0; dt < 4; dt++) oacc[dt] = (f32x4){0.f, 0.f, 0.f, 0.f};
  f32x4 lacc = (f32x4){0.f, 0.f, 0.f, 0.f};

  const short* kbase = kg + (size_t)bh * SEQ * DK;
  const short* vbase = vt + (size_t)bh * DK * SEQ;
  // rel rows indexed as (j - i0 + 1984) + offset; fold head base + (1984 - i0).
  const short* rbase = relk + ((size_t)(h * NPOS + 1984 - i0)) * DK;

  const int rb_w = 48 - 16 * wl;

  // stage this half's V^T tile at j0n: 8 cp16 per half, 2 per wave (conflict-free)
  auto STAGEV = [&](int j0n) {
#pragma unroll
    for (int cc = 0; cc < 2; cc++) {
      const int c = wl * 2 + cc;
      cp16(vbase + (size_t)(c * 8 + (lane >> 3)) * SEQ + j0n + (lane & 7) * 8,
           &VtS[half][c * 512]);
    }
  };

  // ---- prologue ----
  // rel slots 16..127 = rows jb+16..jb+127 (14 cp16 per half, wave-split)
#pragma unroll
  for (int cc = 0; cc < 4; cc++) {
    const int c = wl + cc * 4;
    if (c < 14)
      cp16(rbase + (size_t)(jb + 16) * DK + c * 512 + lane * 8,
           &RelR[half][1024 + c * 512]);
  }
  STAGEV(jb);
  // carry init: bpermuted rel window 0 of tile 0 (direct global, swizzled cols)
  f32x4 bpp_carry;
  {
    const short* rl = rbase + (size_t)(jb + rb_w + l15) * DK;
    short8 b0 = *(const short8*)(rl + ((quad * 8) ^ x));
    short8 b1 = *(const short8*)(rl + ((quad * 8 + 32) ^ x));
    f32x4 a = (f32x4){0.f, 0.f, 0.f, 0.f};
    a = __builtin_amdgcn_mfma_f32_16x16x32_bf16(qpA[0], b0, a, 0, 0, 0);
    a = __builtin_amdgcn_mfma_f32_16x16x32_bf16(qpA[1], b1, a, 0, 0, 0);
#pragma unroll
    for (int g = 0; g < 4; g++)
      bpp_carry[g] = __int_as_float(__builtin_amdgcn_ds_bpermute(idxg[g], __float_as_int(a[g])));
  }
  __syncthreads();   // (A0) prologue staging landed

  for (int jt = 0; jt < 16; jt++) {
    const int j0 = jb + jt * 64;
    const int rowoff = (jt & 1) * 64;   // ring chunk parity for this tile's base

    // QK^T: K fragments direct from global (independent batch, latency-tolerant)
    f32x4 sacc[4];
#pragma unroll
    for (int nt = 0; nt < 4; nt++) {
      const short* kr = kbase + (size_t)(j0 + nt * 16 + l15) * DK + quad * 8;
      short8 b0 = *(const short8*)kr;
      short8 b1 = *(const short8*)(kr + 32);
      f32x4 a = (f32x4){0.f, 0.f, 0.f, 0.f};
      a = __builtin_amdgcn_mfma_f32_16x16x32_bf16(qcA[0], b0, a, 0, 0, 0);
      a = __builtin_amdgcn_mfma_f32_16x16x32_bf16(qcA[1], b1, a, 0, 0, 0);
      sacc[nt] = a;
    }

    f32x4 bpp = bpp_carry;

#pragma unroll
    for (int nt = 0; nt < 4; nt++) {
      f32x4 rcur;
      {
        // ring slot for global row j0+16+rb_w+nt*16+l15 (jb ≡ 0 mod 128)
        const int slot = (rowoff + 16 + rb_w + nt * 16 + l15) & 127;
        const short* rl = &RelR[half][slot * 64];
        short8 b0 = *(const short8*)(rl + ((quad * 8) ^ x));
        short8 b1 = *(const short8*)(rl + ((quad * 8 + 32) ^ x));
        f32x4 a = (f32x4){0.f, 0.f, 0.f, 0.f};
        a = __builtin_amdgcn_mfma_f32_16x16x32_bf16(qpA[0], b0, a, 0, 0, 0);
        a = __builtin_amdgcn_mfma_f32_16x16x32_bf16(qpA[1], b1, a, 0, 0, 0);
        rcur = a;
      }
      f32x4 bpc;
#pragma unroll
      for (int g = 0; g < 4; g++)
        bpc[g] = __int_as_float(__builtin_amdgcn_ds_bpermute(idxg[g], __float_as_int(rcur[g])));
#pragma unroll
      for (int g = 0; g < 4; g++) {
        const float relv = selg[g] ? bpp[g] : bpc[g];
        const float s = sacc[nt][g] + relv;
        const float p = __expf(s - 12.0f);
        const int prow = quad * 4 + g;
        Pw[w][prow][(nt * 16 + l15) ^ ((prow & 7) << 3)] = (short)f2bf(p);
      }
      bpp = bpc;
    }
    bpp_carry = bpp;   // window 4 of this tile == window 0 of the next

    __syncthreads();   // (C) ring reads done; drains V prefetch issued last iter

    // rel prefetch for tile jt+1: rows [j0+128, j0+192) -> slots [rowoff, rowoff+64)
    if (jt < 15) {
      const short* rsrc = rbase + (size_t)(j0 + 128) * DK;
#pragma unroll
      for (int cc = 0; cc < 2; cc++) {
        const int c = wl * 2 + cc;
        cp16(rsrc + c * 512 + lane * 8, &RelR[half][rowoff * 64 + c * 512]);
      }
    }

    // PV: hides the ring prefetch; VtS[half] staged last iter (drained at C)
#pragma unroll
    for (int ks = 0; ks < 2; ks++) {
      short8 pA = *(const short8*)&Pw[w][l15][(ks * 32 + quad * 8) ^ x];
      lacc = __builtin_amdgcn_mfma_f32_16x16x32_bf16(pA, ones8, lacc, 0, 0, 0);
#pragma unroll
      for (int dt = 0; dt < 4; dt++) {
        const short* vl = &VtS[half][(dt * 16 + l15) * 64 + ((ks * 32 + quad * 8) ^ x)];
        short8 vB = *(const short8*)vl;
        oacc[dt] = __builtin_amdgcn_mfma_f32_16x16x32_bf16(pA, vB, oacc[dt], 0, 0, 0);
      }
    }

    __syncthreads();   // (A) PV reads done -> safe to overwrite VtS; ring pref drained
    if (jt < 15) STAGEV(j0 + 64);   // lands by next tile's (C)
  }

  // ---- in-block merge: half 1 parks partials, half 0 combines + writes oh ----
  float* oscr = (float*)&VtS[0][0];   // [4 pairs][16 rows][64 d] f32 = 16 KB
  float* lscr = (float*)&RelR[0][0];  // [4 pairs][16 rows] f32
  if (w >= 4) {
#pragma unroll
    for (int g = 0; g < 4; g++) {
      const int r = quad * 4 + g;
#pragma unroll
      for (int dt = 0; dt < 4; dt++)
        oscr[(wl * 16 + r) * 64 + dt * 16 + l15] = oacc[dt][g];
      if (l15 == 0) lscr[wl * 16 + r] = lacc[g];
    }
  }
  __syncthreads();
  if (w < 4) {
    const int b = bh >> 3, hh = bh & 7;
#pragma unroll
    for (int g = 0; g < 4; g++) {
      const int r = quad * 4 + g;
      const float linv = 1.0f / (lacc[g] + lscr[wl * 16 + r]);
      const size_t mrow = (size_t)(b * SEQ + i0 + wl * 16 + r) * HD + hh * 64;
#pragma unroll
      for (int dt = 0; dt < 4; dt++) {
        const float o = oacc[dt][g] + oscr[(wl * 16 + r) * 64 + dt * 16 + l15];
        oh[mrow + dt * 16 + l15] = (short)f2bf(o * linv);
      }
    }
  }
}

// ---------------- launch ----------------
extern "C" void kernel_launch(void* const* d_in, const int* in_sizes, int n_in,
                              void* d_out, int out_size, void* d_ws, size_t ws_size,
                              hipStream_t stream) {
  (void)in_sizes; (void)n_in; (void)out_size; (void)ws_size;
  const float* x    = (const float*)d_in[0];
  const float* Wq   = (const float*)d_in[1];
  const float* Wk   = (const float*)d_in[2];
  const float* Wv   = (const float*)d_in[3];
  const float* Wrel = (const float*)d_in[4];
  const float* Wout = (const float*)d_in[5];
  const float* bout = (const float*)d_in[6];
  const float* cb   = (const float*)d_in[7];
  const float* pb   = (const float*)d_in[8];
  float* out = (float*)d_out;

  char* ws = (char*)d_ws;
  bf16*  relk = (bf16*)(ws + OB_RELK);
  bf16*  qc   = (bf16*)(ws + OB_QC);
  bf16*  qp   = (bf16*)(ws + OB_QP);
  bf16*  kk   = (bf16*)(ws + OB_K);
  short* vt   = (short*)(ws + OB_V);    // V^T written directly by gemm_qr (swizzled)
  short* oh   = (short*)(ws + OB_OH);   // written directly by attn (merged)
  short* embh = (short*)(ws + OB_EMBH);
  short* embl = (short*)(ws + OB_EMBL);
  short* xh   = (short*)(ws + OB_XH);
  short* xl   = (short*)(ws + OB_XL);
  short* wqh  = (short*)(ws + OB_WQKVH);
  short* wql  = (short*)(ws + OB_WQKVL);
  short* woh  = (short*)(ws + OB_WOH);
  short* wol  = (short*)(ws + OB_WOL);
  short* wrh  = (short*)(ws + OB_WRH);
  short* wrl  = (short*)(ws + OB_WRL);

  hipLaunchKernelGGL(prep_all, dim3(5216), dim3(256), 0, stream,
                     x, Wq, Wk, Wv, Wout, Wrel,
                     embh, embl, xh, xl, wqh, wql, woh, wol, wrh, wrl);
  hipLaunchKernelGGL(gemm_qr, dim3(512), dim3(256), 0, stream,
                     xh, xl, wqh, wql, embh, embl, wrh, wrl,
                     cb, pb, qc, qp, kk, vt, relk);
  hipLaunchKernelGGL(attn_mfma4, dim3(512), dim3(512), 0, stream,
                     (const short*)qc, (const short*)qp, (const short*)kk,
                     (const short*)vt, (const short*)relk, oh);
  hipLaunchKernelGGL(out_gemm, dim3(64, 12), dim3(256), 0, stream,
                     (const short*)oh, woh, wol, bout, out);
}

// Round 13
// 196.910 us; speedup vs baseline: 1.4154x; 1.0390x over previous
//
#include <hip/hip_runtime.h>
#include <hip/hip_bf16.h>
#include <math.h>
#include <stdint.h>

typedef __hip_bfloat16 bf16;
typedef __attribute__((ext_vector_type(8))) short short8;  // 8 bf16 = 4 VGPRs
typedef __attribute__((ext_vector_type(4))) float f32x4;

#define SEQ   2048
#define NPOS  4095          // 2*SEQ-1
#define DIMM  768
#define HEADS 8
#define DK    64
#define HD    512           // HEADS*DK
#define BATCH 2
#define BH    16            // BATCH*HEADS
#define ROWS  4096          // BATCH*SEQ

// ---------------- workspace layout (BYTE offsets), ~44.4 MB ----------------
#define OB_RELK  ((size_t)0)                      // bf16 [8][4095][64], col-swizzled
#define OB_QC    ((size_t)4194304)
#define OB_QP    ((size_t)8388608)
#define OB_K     ((size_t)12582912)
#define OB_V     ((size_t)16777216)               // V^T [bh][64][2048], chunk-swizzled
#define OB_OH    ((size_t)20971520)               // bf16 [4096][512]
// aliased (disjoint lifetimes):
#define OB_EMBH  OB_OH                            // dead after gemm_qr
#define OB_EMBL  ((size_t)(OB_OH + 1572864))
#define OB_XH    ((size_t)25165824)               // dead after gemm_qr
#define OB_XL    ((size_t)31457280)
#define OB_WQKVH ((size_t)37748736)               // dead after gemm_qr
#define OB_WQKVL ((size_t)40108032)
#define OB_WOH   ((size_t)42467328)               // out-proj weights
#define OB_WOL   ((size_t)43253760)
#define OB_WRH   ((size_t)44040192)
#define OB_WRL   ((size_t)44236800)

// RNE float -> bf16 bits (finite inputs only)
__device__ __forceinline__ unsigned f2bf(float f) {
  unsigned u = __float_as_uint(f);
  return (u + 0x7fffu + ((u >> 16) & 1u)) >> 16;
}
__device__ __forceinline__ void split2(float v, unsigned& hb, unsigned& lb) {
  hb = f2bf(v);
  const float back = __uint_as_float(hb << 16);
  lb = f2bf(v - back);
}

// async global->LDS 16B copy (m97 pattern; CK-style addrspace casts).
// l must be wave-uniform; HW writes l + lane*16. g is per-lane.
__device__ __forceinline__ void cp16(const short* g, short* l) {
  __builtin_amdgcn_global_load_lds(
      (__attribute__((address_space(1))) void*)(uintptr_t)(g),
      (__attribute__((address_space(3))) void*)(uint32_t)(uintptr_t)(l),
      16, 0, 0);
}

// ---------------- 1. fused prep: pos_emb + conv_split + 5 transposes ----------------
__global__ __launch_bounds__(256) void prep_all(
    const float* __restrict__ x,
    const float* __restrict__ Wq, const float* __restrict__ Wk,
    const float* __restrict__ Wv, const float* __restrict__ Wout,
    const float* __restrict__ Wrel,
    short* __restrict__ eh, short* __restrict__ el,
    short* __restrict__ xh, short* __restrict__ xl,
    short* __restrict__ wqkvh, short* __restrict__ wqkvl,
    short* __restrict__ woh, short* __restrict__ wol,
    short* __restrict__ wrh, short* __restrict__ wrl) {
  __shared__ float tile[32][33];
  const int blk = blockIdx.x;
  const int t = threadIdx.x;

  if (blk < 512) {
    const int row = blk * 8 + (t >> 5);
    const int j   = t & 31;
    if (row >= NPOS) {
      for (int c = j; c < 192; c += 32) { eh[(size_t)row * 192 + c] = 0; el[(size_t)row * 192 + c] = 0; }
      return;
    }
    const float dist = (float)(row - (SEQ - 1));
    const float ad   = fabsf(dist);
    const float hl    = exp2f(3.0f + 8.0f * (float)j / 31.0f);
    const float f_exp = exp2f(-ad / hl);
    const float width = exp2f((float)(j + 1)) - 1.0f;
    const float f_cm  = (width > ad) ? 1.0f : 0.0f;
    float prob;
    if (ad > 0.0f) {
      const float c   = 4.0f * (float)((j + 1) * (j + 1));
      const float r   = (float)(j + 1) / 16.0f;
      const float lu  = (c - 1.0f) * logf(ad) - r * ad;
      const float ln_ = lgammaf(c) - c * logf(r);
      prob = expf(lu - ln_) + 1e-8f;
    } else {
      prob = 1e-8f;
    }
    float mx = prob;
    for (int off = 16; off; off >>= 1) mx = fmaxf(mx, __shfl_xor(mx, off, 32));
    const float f_g = prob / mx;
    const float s = (dist > 0.f) ? 1.f : ((dist < 0.f) ? -1.f : 0.f);
    const float vals[6] = {f_exp, f_cm, f_g, s * f_exp, s * f_cm, s * f_g};
    short* ph = eh + (size_t)row * 192;
    short* pl = el + (size_t)row * 192;
#pragma unroll
    for (int q = 0; q < 6; q++) {
      unsigned hb, lb;
      split2(vals[q], hb, lb);
      ph[q * 32 + j] = (short)hb;
      pl[q * 32 + j] = (short)lb;
    }
    return;
  }

  if (blk < 3584) {
    const int i = (blk - 512) * 256 + t;
    const float4 v = ((const float4*)x)[i];
    unsigned h0, l0, h1, l1, h2, l2, h3, l3;
    split2(v.x, h0, l0); split2(v.y, h1, l1); split2(v.z, h2, l2); split2(v.w, h3, l3);
    *(uint2*)&xh[(size_t)i * 4] = make_uint2(h0 | (h1 << 16), h2 | (h3 << 16));
    *(uint2*)&xl[(size_t)i * 4] = make_uint2(l0 | (l1 << 16), l2 | (l3 << 16));
    return;
  }

  const float* src; short* dh; short* dl; int R, C, local;
  if (blk < 3968)      { local = blk - 3584; src = Wq;   dh = wqkvh;               dl = wqkvl;               R = DIMM; C = HD; }
  else if (blk < 4352) { local = blk - 3968; src = Wk;   dh = wqkvh + 512 * DIMM;  dl = wqkvl + 512 * DIMM;  R = DIMM; C = HD; }
  else if (blk < 4736) { local = blk - 4352; src = Wv;   dh = wqkvh + 1024 * DIMM; dl = wqkvl + 1024 * DIMM; R = DIMM; C = HD; }
  else if (blk < 5120) { local = blk - 4736; src = Wout; dh = woh;  dl = wol;  R = HD;  C = DIMM; }
  else                 { local = blk - 5120; src = Wrel; dh = wrh;  dl = wrl;  R = 192; C = HD; }
  const int ctiles = C / 32;
  const int c0 = (local % ctiles) * 32, r0 = (local / ctiles) * 32;
  {
    const int lr = t >> 3, lc = (t & 7) * 4;
    const float4 v = *(const float4*)&src[(size_t)(r0 + lr) * C + c0 + lc];
    tile[lr][lc] = v.x; tile[lr][lc + 1] = v.y; tile[lr][lc + 2] = v.z; tile[lr][lc + 3] = v.w;
  }
  __syncthreads();
  const int nn = t >> 3, kb = (t & 7) * 4;
  unsigned hb[4], lb[4];
#pragma unroll
  for (int e = 0; e < 4; e++) split2(tile[kb + e][nn], hb[e], lb[e]);
  const size_t o = (size_t)(c0 + nn) * R + r0 + kb;
  *(uint2*)&dh[o] = make_uint2(hb[0] | (hb[1] << 16), hb[2] | (hb[3] << 16));
  *(uint2*)&dl[o] = make_uint2(lb[0] | (lb[1] << 16), lb[2] | (lb[3] << 16));
}

// ---------------- 2. unified qkv+relk GEMM: 8 waves, dbuf cp16 ----------------
// R13: grid 512 = 2 blocks/CU was wave-starved (8 waves/CU). Same 128x128 tile,
// 512 threads: wave grid 2x4, each wave 64x32 output (acc[4][2]); staging = 1
// cp16 per array per wave (identical LDS image). 16 waves/CU.
__global__ __launch_bounds__(512) void gemm_qr(
    const short* __restrict__ xh, const short* __restrict__ xl,
    const short* __restrict__ wqkvh, const short* __restrict__ wqkvl,
    const short* __restrict__ eh, const short* __restrict__ el,
    const short* __restrict__ wrh, const short* __restrict__ wrl,
    const float* __restrict__ cb, const float* __restrict__ pb,
    bf16* __restrict__ oq, bf16* __restrict__ oqp,
    bf16* __restrict__ ok, short* __restrict__ vtw,
    bf16* __restrict__ relk) {
  __shared__ short AsH[2][128][32];
  __shared__ short AsL[2][128][32];
  __shared__ short BsH[2][128][32];
  __shared__ short BsL[2][128][32];

  const int bx = blockIdx.x;
  const bool isq = bx < 384;
  const int lbx = isq ? bx : bx - 384;
  const int mt = lbx & 31, ntile = lbx >> 5;
  const int m0 = mt * 128, n0 = ntile * 128;
  const int KD = isq ? DIMM : 192;
  const short* Ah = isq ? xh : eh;
  const short* Al = isq ? xl : el;
  const short* Bh = isq ? wqkvh : wrh;
  const short* Bl = isq ? wqkvl : wrl;

  const int t = threadIdx.x, lane = t & 63, w = t >> 6;   // w = 0..7
  const int quad = lane >> 4, l15 = lane & 15;
  const int wm = (w >> 2) * 64, wn = (w & 3) * 32;        // 2x4 wave grid

  const int srow = w * 16 + (lane >> 2);   // staging row: wave covers 16 rows
  const int skof = (lane & 3) * 8;         // shorts within 64B row

  auto STAGE = [&](int bb, int k0) {
    const size_t ra = (size_t)(m0 + srow) * KD + k0 + skof;
    const size_t rb = (size_t)(n0 + srow) * KD + k0 + skof;
    cp16(&Ah[ra], &AsH[bb][w * 16][0]);
    cp16(&Al[ra], &AsL[bb][w * 16][0]);
    cp16(&Bh[rb], &BsH[bb][w * 16][0]);
    cp16(&Bl[rb], &BsL[bb][w * 16][0]);
  };

  f32x4 acc[4][2];
#pragma unroll
  for (int i = 0; i < 4; i++)
#pragma unroll
    for (int j = 0; j < 2; j++) acc[i][j] = (f32x4){0.f, 0.f, 0.f, 0.f};

  STAGE(0, 0);
  __syncthreads();   // tile 0 landed (vmcnt drain)

  int bb = 0;
  for (int k0 = 0; k0 < KD; k0 += 32) {
    if (k0 + 32 < KD) STAGE(bb ^ 1, k0 + 32);   // rides under this step's compute

    short8 amh[4], aml[4], bnh[2], bnl[2];
#pragma unroll
    for (int i = 0; i < 4; i++) {
      amh[i] = *(const short8*)&AsH[bb][wm + i * 16 + l15][quad * 8];
      aml[i] = *(const short8*)&AsL[bb][wm + i * 16 + l15][quad * 8];
    }
#pragma unroll
    for (int j = 0; j < 2; j++) {
      bnh[j] = *(const short8*)&BsH[bb][wn + j * 16 + l15][quad * 8];
      bnl[j] = *(const short8*)&BsL[bb][wn + j * 16 + l15][quad * 8];
    }
#pragma unroll
    for (int i = 0; i < 4; i++) {
#pragma unroll
      for (int j = 0; j < 2; j++) {
        acc[i][j] = __builtin_amdgcn_mfma_f32_16x16x32_bf16(amh[i], bnh[j], acc[i][j], 0, 0, 0);
        acc[i][j] = __builtin_amdgcn_mfma_f32_16x16x32_bf16(amh[i], bnl[j], acc[i][j], 0, 0, 0);
        acc[i][j] = __builtin_amdgcn_mfma_f32_16x16x32_bf16(aml[i], bnh[j], acc[i][j], 0, 0, 0);
      }
    }

    __syncthreads();   // drains prefetch (hidden under MFMAs); protects swap
    bb ^= 1;
  }

  if (isq) {
    const int sel = ntile >> 2;   // 0=q,1=k,2=v
    if (sel == 2) {
      // V^T write, swizzled: s' = s ^ ((d&7)<<3) within the 64-aligned chunk.
#pragma unroll
      for (int i = 0; i < 4; i++) {
#pragma unroll
        for (int j = 0; j < 2; j++) {
          const int n = n0 + wn + j * 16 + l15;
          const int hd_ = n & 511, hh = hd_ >> 6, d = hd_ & 63;
          const int m = m0 + wm + i * 16 + quad * 4;
          const int b = m >> 11, s = m & 2047;
          const int s_swz = s ^ ((d & 7) << 3);
          const uint2 pk = make_uint2(
              f2bf(acc[i][j][0]) | (f2bf(acc[i][j][1]) << 16),
              f2bf(acc[i][j][2]) | (f2bf(acc[i][j][3]) << 16));
          *(uint2*)&vtw[(((size_t)(b * HEADS + hh) * DK + d) * SEQ) + s_swz] = pk;
        }
      }
    } else {
#pragma unroll
      for (int i = 0; i < 4; i++) {
#pragma unroll
        for (int j = 0; j < 2; j++) {
          const int n = n0 + wn + j * 16 + l15;
          const int hd_ = n & 511, hh = hd_ >> 6, d = hd_ & 63;
#pragma unroll
          for (int g = 0; g < 4; g++) {
            const int m = m0 + wm + i * 16 + quad * 4 + g;
            const int b = m >> 11, s = m & 2047;
            const size_t idx = (((size_t)(b * HEADS + hh) * SEQ) + s) * DK + d;
            const float v = acc[i][j][g];
            if (sel == 0) {
              const float sv = v * 0.125f;   // dk^-0.5
              oq[idx]  = __float2bfloat16(sv + cb[hh * DK + d]);
              oqp[idx] = __float2bfloat16(sv + pb[hh * DK + d]);
            } else {
              ok[idx] = __float2bfloat16(v);
            }
          }
        }
      }
    }
  } else {
    // relk write, swizzled: d' = d ^ ((m&7)<<3)
#pragma unroll
    for (int i = 0; i < 4; i++) {
#pragma unroll
      for (int j = 0; j < 2; j++) {
        const int n = n0 + wn + j * 16 + l15;
        const int hh = n >> 6, d = n & 63;
#pragma unroll
        for (int g = 0; g < 4; g++) {
          const int m = m0 + wm + i * 16 + quad * 4 + g;
          if (m < NPOS)
            relk[((size_t)hh * NPOS + m) * DK + (d ^ ((m & 7) << 3))] =
                __float2bfloat16(acc[i][j][g]);
        }
      }
    }
  }
}

// ---------------- 3. out-projection GEMM, 64x64 tiles, dbuf cp16 (R12) ----------------
__global__ __launch_bounds__(256) void out_gemm(
    const short* __restrict__ Ahp,
    const short* __restrict__ Bhp, const short* __restrict__ Blp,
    const float* __restrict__ bias, float* __restrict__ ofp) {
  __shared__ short AsH[2][64][32];
  __shared__ short BsH[2][64][32];
  __shared__ short BsL[2][64][32];

  const int t = threadIdx.x, lane = t & 63, w = t >> 6;
  const int quad = lane >> 4, l15 = lane & 15;
  const int wm = (w >> 1) * 32, wn = (w & 1) * 32;
  const int m0 = blockIdx.x * 64, n0 = blockIdx.y * 64;
  const int srow = w * 16 + (lane >> 2);   // staging row (wave w covers 16 rows)
  const int skof = (lane & 3) * 8;

  auto STAGE = [&](int bb, int k0) {
    const size_t ra = (size_t)(m0 + srow) * HD + k0 + skof;
    const size_t rb = (size_t)(n0 + srow) * HD + k0 + skof;
    cp16(&Ahp[ra], &AsH[bb][w * 16][0]);
    cp16(&Bhp[rb], &BsH[bb][w * 16][0]);
    cp16(&Blp[rb], &BsL[bb][w * 16][0]);
  };

  f32x4 acc[2][2];
#pragma unroll
  for (int i = 0; i < 2; i++)
#pragma unroll
    for (int j = 0; j < 2; j++) acc[i][j] = (f32x4){0.f, 0.f, 0.f, 0.f};

  STAGE(0, 0);
  __syncthreads();

  int bb = 0;
  for (int k0 = 0; k0 < HD; k0 += 32) {
    if (k0 + 32 < HD) STAGE(bb ^ 1, k0 + 32);

    short8 amh[2], bnh[2], bnl[2];
#pragma unroll
    for (int i = 0; i < 2; i++) {
      amh[i] = *(const short8*)&AsH[bb][wm + i * 16 + l15][quad * 8];
      bnh[i] = *(const short8*)&BsH[bb][wn + i * 16 + l15][quad * 8];
      bnl[i] = *(const short8*)&BsL[bb][wn + i * 16 + l15][quad * 8];
    }
#pragma unroll
    for (int i = 0; i < 2; i++) {
#pragma unroll
      for (int j = 0; j < 2; j++) {
        acc[i][j] = __builtin_amdgcn_mfma_f32_16x16x32_bf16(amh[i], bnh[j], acc[i][j], 0, 0, 0);
        acc[i][j] = __builtin_amdgcn_mfma_f32_16x16x32_bf16(amh[i], bnl[j], acc[i][j], 0, 0, 0);
      }
    }

    __syncthreads();
    bb ^= 1;
  }

#pragma unroll
  for (int i = 0; i < 2; i++) {
#pragma unroll
    for (int j = 0; j < 2; j++) {
      const int n = n0 + wn + j * 16 + l15;
      const float bv = bias[n];
#pragma unroll
      for (int g = 0; g < 4; g++) {
        const int m = m0 + wm + i * 16 + quad * 4 + g;
        ofp[(size_t)m * DIMM + n] = acc[i][j][g] + bv;
      }
    }
  }
}

// ---------------- 4. attention: 8-wave, both j-halves per block, in-kernel merge (R11, unchanged) ----------------
__global__ __launch_bounds__(512) void attn_mfma4(
    const short* __restrict__ qc, const short* __restrict__ qp,
    const short* __restrict__ kg, const short* __restrict__ vt,
    const short* __restrict__ relk,
    short* __restrict__ oh) {
  __shared__ __align__(16) short RelR[2][128 * 64];  // per-half 2-chunk rel ring
  __shared__ __align__(16) short VtS[2][64 * 64];    // per-half V^T tile (single)
  __shared__ __align__(16) short Pw[8][16][64];      // per-wave P, XOR-swizzled

  const int bid = blockIdx.x;
  const int swz = (bid & 7) * 64 + (bid >> 3);    // bijective: 512 % 8 == 0
  const int i0  = (swz & 31) * 64;
  const int bh  = swz >> 5;
  const int h   = bh & 7;

  const int t    = threadIdx.x;
  const int lane = t & 63;
  const int w    = t >> 6;          // 0..7
  const int wl   = w & 3;           // i-sub-wave within half
  const int half = w >> 2;          // j-half
  const int jb   = half * (SEQ / 2);
  const int quad = lane >> 4;
  const int l15  = lane & 15;
  const int x    = (l15 & 7) << 3;  // swizzle key (shorts)

  short8 qcA[2], qpA[2];
  {
    const size_t qrow = ((size_t)bh * SEQ + i0 + wl * 16 + l15) * DK + quad * 8;
    qcA[0] = *(const short8*)(qc + qrow);
    qcA[1] = *(const short8*)(qc + qrow + 32);
    qpA[0] = *(const short8*)(qp + qrow);
    qpA[1] = *(const short8*)(qp + qrow + 32);
  }

  int idxg[4]; bool selg[4];
#pragma unroll
  for (int g = 0; g < 4; g++) {
    const int r = quad * 4 + g;
    idxg[g] = (((lane & 48) | ((l15 + 15 - r) & 15)) << 2);
    selg[g] = (l15 <= r);
  }

  short8 ones8;
#pragma unroll
  for (int e = 0; e < 8; e++) ones8[e] = (short)0x3F80;   // bf16 1.0

  f32x4 oacc[4];
#pragma unroll
  for (int dt = 0; dt < 4; dt++) oacc[dt] = (f32x4){0.f, 0.f, 0.f, 0.f};
  f32x4 lacc = (f32x4){0.f, 0.f, 0.f, 0.f};

  const short* kbase = kg + (size_t)bh * SEQ * DK;
  const short* vbase = vt + (size_t)bh * DK * SEQ;
  // rel rows indexed as (j - i0 + 1984) + offset; fold head base + (1984 - i0).
  const short* rbase = relk + ((size_t)(h * NPOS + 1984 - i0)) * DK;

  const int rb_w = 48 - 16 * wl;

  // stage this half's V^T tile at j0n: 8 cp16 per half, 2 per wave (conflict-free)
  auto STAGEV = [&](int j0n) {
#pragma unroll
    for (int cc = 0; cc < 2; cc++) {
      const int c = wl * 2 + cc;
      cp16(vbase + (size_t)(c * 8 + (lane >> 3)) * SEQ + j0n + (lane & 7) * 8,
           &VtS[half][c * 512]);
    }
  };

  // ---- prologue ----
  // rel slots 16..127 = rows jb+16..jb+127 (14 cp16 per half, wave-split)
#pragma unroll
  for (int cc = 0; cc < 4; cc++) {
    const int c = wl + cc * 4;
    if (c < 14)
      cp16(rbase + (size_t)(jb + 16) * DK + c * 512 + lane * 8,
           &RelR[half][1024 + c * 512]);
  }
  STAGEV(jb);
  // carry init: bpermuted rel window 0 of tile 0 (direct global, swizzled cols)
  f32x4 bpp_carry;
  {
    const short* rl = rbase + (size_t)(jb + rb_w + l15) * DK;
    short8 b0 = *(const short8*)(rl + ((quad * 8) ^ x));
    short8 b1 = *(const short8*)(rl + ((quad * 8 + 32) ^ x));
    f32x4 a = (f32x4){0.f, 0.f, 0.f, 0.f};
    a = __builtin_amdgcn_mfma_f32_16x16x32_bf16(qpA[0], b0, a, 0, 0, 0);
    a = __builtin_amdgcn_mfma_f32_16x16x32_bf16(qpA[1], b1, a, 0, 0, 0);
#pragma unroll
    for (int g = 0; g < 4; g++)
      bpp_carry[g] = __int_as_float(__builtin_amdgcn_ds_bpermute(idxg[g], __float_as_int(a[g])));
  }
  __syncthreads();   // (A0) prologue staging landed

  for (int jt = 0; jt < 16; jt++) {
    const int j0 = jb + jt * 64;
    const int rowoff = (jt & 1) * 64;   // ring chunk parity for this tile's base

    // QK^T: K fragments direct from global (independent batch, latency-tolerant)
    f32x4 sacc[4];
#pragma unroll
    for (int nt = 0; nt < 4; nt++) {
      const short* kr = kbase + (size_t)(j0 + nt * 16 + l15) * DK + quad * 8;
      short8 b0 = *(const short8*)kr;
      short8 b1 = *(const short8*)(kr + 32);
      f32x4 a = (f32x4){0.f, 0.f, 0.f, 0.f};
      a = __builtin_amdgcn_mfma_f32_16x16x32_bf16(qcA[0], b0, a, 0, 0, 0);
      a = __builtin_amdgcn_mfma_f32_16x16x32_bf16(qcA[1], b1, a, 0, 0, 0);
      sacc[nt] = a;
    }

    f32x4 bpp = bpp_carry;

#pragma unroll
    for (int nt = 0; nt < 4; nt++) {
      f32x4 rcur;
      {
        // ring slot for global row j0+16+rb_w+nt*16+l15 (jb ≡ 0 mod 128)
        const int slot = (rowoff + 16 + rb_w + nt * 16 + l15) & 127;
        const short* rl = &RelR[half][slot * 64];
        short8 b0 = *(const short8*)(rl + ((quad * 8) ^ x));
        short8 b1 = *(const short8*)(rl + ((quad * 8 + 32) ^ x));
        f32x4 a = (f32x4){0.f, 0.f, 0.f, 0.f};
        a = __builtin_amdgcn_mfma_f32_16x16x32_bf16(qpA[0], b0, a, 0, 0, 0);
        a = __builtin_amdgcn_mfma_f32_16x16x32_bf16(qpA[1], b1, a, 0, 0, 0);
        rcur = a;
      }
      f32x4 bpc;
#pragma unroll
      for (int g = 0; g < 4; g++)
        bpc[g] = __int_as_float(__builtin_amdgcn_ds_bpermute(idxg[g], __float_as_int(rcur[g])));
#pragma unroll
      for (int g = 0; g < 4; g++) {
        const float relv = selg[g] ? bpp[g] : bpc[g];
        const float s = sacc[nt][g] + relv;
        const float p = __expf(s - 12.0f);
        const int prow = quad * 4 + g;
        Pw[w][prow][(nt * 16 + l15) ^ ((prow & 7) << 3)] = (short)f2bf(p);
      }
      bpp = bpc;
    }
    bpp_carry = bpp;   // window 4 of this tile == window 0 of the next

    __syncthreads();   // (C) ring reads done; drains V prefetch issued last iter

    // rel prefetch for tile jt+1: rows [j0+128, j0+192) -> slots [rowoff, rowoff+64)
    if (jt < 15) {
      const short* rsrc = rbase + (size_t)(j0 + 128) * DK;
#pragma unroll
      for (int cc = 0; cc < 2; cc++) {
        const int c = wl * 2 + cc;
        cp16(rsrc + c * 512 + lane * 8, &RelR[half][rowoff * 64 + c * 512]);
      }
    }

    // PV: hides the ring prefetch; VtS[half] staged last iter (drained at C)
#pragma unroll
    for (int ks = 0; ks < 2; ks++) {
      short8 pA = *(const short8*)&Pw[w][l15][(ks * 32 + quad * 8) ^ x];
      lacc = __builtin_amdgcn_mfma_f32_16x16x32_bf16(pA, ones8, lacc, 0, 0, 0);
#pragma unroll
      for (int dt = 0; dt < 4; dt++) {
        const short* vl = &VtS[half][(dt * 16 + l15) * 64 + ((ks * 32 + quad * 8) ^ x)];
        short8 vB = *(const short8*)vl;
        oacc[dt] = __builtin_amdgcn_mfma_f32_16x16x32_bf16(pA, vB, oacc[dt], 0, 0, 0);
      }
    }

    __syncthreads();   // (A) PV reads done -> safe to overwrite VtS; ring pref drained
    if (jt < 15) STAGEV(j0 + 64);   // lands by next tile's (C)
  }

  // ---- in-block merge: half 1 parks partials, half 0 combines + writes oh ----
  float* oscr = (float*)&VtS[0][0];   // [4 pairs][16 rows][64 d] f32 = 16 KB
  float* lscr = (float*)&RelR[0][0];  // [4 pairs][16 rows] f32
  if (w >= 4) {
#pragma unroll
    for (int g = 0; g < 4; g++) {
      const int r = quad * 4 + g;
#pragma unroll
      for (int dt = 0; dt < 4; dt++)
        oscr[(wl * 16 + r) * 64 + dt * 16 + l15] = oacc[dt][g];
      if (l15 == 0) lscr[wl * 16 + r] = lacc[g];
    }
  }
  __syncthreads();
  if (w < 4) {
    const int b = bh >> 3, hh = bh & 7;
#pragma unroll
    for (int g = 0; g < 4; g++) {
      const int r = quad * 4 + g;
      const float linv = 1.0f / (lacc[g] + lscr[wl * 16 + r]);
      const size_t mrow = (size_t)(b * SEQ + i0 + wl * 16 + r) * HD + hh * 64;
#pragma unroll
      for (int dt = 0; dt < 4; dt++) {
        const float o = oacc[dt][g] + oscr[(wl * 16 + r) * 64 + dt * 16 + l15];
        oh[mrow + dt * 16 + l15] = (short)f2bf(o * linv);
      }
    }
  }
}

// ---------------- launch ----------------
extern "C" void kernel_launch(void* const* d_in, const int* in_sizes, int n_in,
                              void* d_out, int out_size, void* d_ws, size_t ws_size,
                              hipStream_t stream) {
  (void)in_sizes; (void)n_in; (void)out_size; (void)ws_size;
  const float* x    = (const float*)d_in[0];
  const float* Wq   = (const float*)d_in[1];
  const float* Wk   = (const float*)d_in[2];
  const float* Wv   = (const float*)d_in[3];
  const float* Wrel = (const float*)d_in[4];
  const float* Wout = (const float*)d_in[5];
  const float* bout = (const float*)d_in[6];
  const float* cb   = (const float*)d_in[7];
  const float* pb   = (const float*)d_in[8];
  float* out = (float*)d_out;

  char* ws = (char*)d_ws;
  bf16*  relk = (bf16*)(ws + OB_RELK);
  bf16*  qc   = (bf16*)(ws + OB_QC);
  bf16*  qp   = (bf16*)(ws + OB_QP);
  bf16*  kk   = (bf16*)(ws + OB_K);
  short* vt   = (short*)(ws + OB_V);    // V^T written directly by gemm_qr (swizzled)
  short* oh   = (short*)(ws + OB_OH);   // written directly by attn (merged)
  short* embh = (short*)(ws + OB_EMBH);
  short* embl = (short*)(ws + OB_EMBL);
  short* xh   = (short*)(ws + OB_XH);
  short* xl   = (short*)(ws + OB_XL);
  short* wqh  = (short*)(ws + OB_WQKVH);
  short* wql  = (short*)(ws + OB_WQKVL);
  short* woh  = (short*)(ws + OB_WOH);
  short* wol  = (short*)(ws + OB_WOL);
  short* wrh  = (short*)(ws + OB_WRH);
  short* wrl  = (short*)(ws + OB_WRL);

  hipLaunchKernelGGL(prep_all, dim3(5216), dim3(256), 0, stream,
                     x, Wq, Wk, Wv, Wout, Wrel,
                     embh, embl, xh, xl, wqh, wql, woh, wol, wrh, wrl);
  hipLaunchKernelGGL(gemm_qr, dim3(512), dim3(512), 0, stream,
                     xh, xl, wqh, wql, embh, embl, wrh, wrl,
                     cb, pb, qc, qp, kk, vt, relk);
  hipLaunchKernelGGL(attn_mfma4, dim3(512), dim3(512), 0, stream,
                     (const short*)qc, (const short*)qp, (const short*)kk,
                     (const short*)vt, (const short*)relk, oh);
  hipLaunchKernelGGL(out_gemm, dim3(64, 12), dim3(256), 0, stream,
                     (const short*)oh, woh, wol, bout, out);
}